// Round 8
// baseline (419142.090 us; speedup 1.0000x reference)
//
#include <hip/hip_runtime.h>
#include <hip/hip_cooperative_groups.h>
#include <math.h>

namespace cg = cooperative_groups;

#define DN 2048
#define LEAF 16
#define NLEAVES 128
#define NB 64
#define CSK 64          /* split-K slices in persistent chetd2 */
#define GBLK 512        /* cooperative grid blocks */
#define EPSF 5.9604645e-08f
#define SAFMINF 1.17549435e-38f

typedef float2 cplx;

struct Ctl {
  float orgnrm;
  int K;
  int ctot[4];
  float rho;
  int nrot;
  int n12, n23;
};

__device__ __forceinline__ cplx mkc(float x, float y){ cplx c; c.x=x; c.y=y; return c; }
__device__ __forceinline__ cplx cmul(cplx a, cplx b){ return mkc(a.x*b.x - a.y*b.y, a.x*b.y + a.y*b.x); }
__device__ __forceinline__ cplx cconj(cplx a){ return mkc(a.x, -a.y); }
__device__ __forceinline__ cplx cadd(cplx a, cplx b){ return mkc(a.x+b.x, a.y+b.y); }
__device__ __forceinline__ cplx cinv(cplx b){
  if (fabsf(b.x) >= fabsf(b.y)) { float r = b.y/b.x; float den = b.x + b.y*r; return mkc(1.f/den, -r/den); }
  else { float r = b.x/b.y; float den = b.x*r + b.y; return mkc(r/den, -1.f/den); }
}

/* ---------------- build H, LDS-tiled transpose reads ---------------- */
__global__ void k_buildH_t(const float* sk, cplx* AH){
  __shared__ float tA[32][33], tB[32][33];
  int C0 = blockIdx.x*32, R0 = blockIdx.y*32;
  int tx = threadIdx.x & 31, ty = threadIdx.x >> 5;
  for (int p=0;p<4;p++){
    int ry = ty + 8*p;
    tA[ry][tx] = sk[(size_t)(R0+ry)*DN + C0+tx];
    tB[ry][tx] = sk[(size_t)(C0+ry)*DN + R0+tx];
  }
  __syncthreads();
  for (int p=0;p<4;p++){
    int cy = ty + 8*p;
    int r = R0 + tx, c = C0 + cy;
    float im;
    if (r > c) im = -tB[cy][tx];
    else if (r < c) im = tA[tx][cy];
    else im = 0.f;
    AH[(size_t)c*DN + r] = mkc(copysignf(0.f, im), im);
  }
}

/* ---------------- persistent cooperative chetd2 (whole tridiagonalization) ---------------- */
__global__ void __launch_bounds__(256) k_chetd2(
    cplx* AH, cplx* wpart, float* ssqpart, cplx* dp, cplx* pa,
    cplx* a0copy, cplx* wvec, cplx* tauA, float* e, float* d)
{
  cg::grid_group gg = cg::this_grid();
  __shared__ float rx[256], ry[256];
  __shared__ float sb_[16];
  int t = threadIdx.x;
  int bid = blockIdx.x, G = gridDim.x;

  for (int j = 0; j <= DN-2; ++j){
    int m = DN-1-j;
    int nb = (m+255)/256;
    int chunk = (m-1 + CSK-1)/CSK;
    cplx* colr = AH + (size_t)j*DN;
    cplx* x = colr + (j+2);   /* raw x[k], k in [0, m-1) */

    /* ---- phase A: split-K gemv partials + ssq/dot/a0 partials ---- */
    for (int tt = bid; tt < nb*CSK; tt += G){
      int b = tt / CSK, s = tt - b*CSK;
      int cc0 = s*chunk, cc1 = cc0+chunk;
      if (cc1 > m-1) cc1 = m-1;
      if (cc0 > m-1) cc0 = m-1;
      int i = b*256 + t;
      if (b == 0){
        float ss = 0.f;
        for (int cc = cc0+t; cc < cc1; cc += 256){ cplx v = x[cc]; ss += v.x*v.x + v.y*v.y; }
        __syncthreads();
        rx[t] = ss; __syncthreads();
        for (int q=128;q>0;q>>=1){ if (t<q) rx[t]+=rx[t+q]; __syncthreads(); }
        if (t==0) ssqpart[s] = rx[0];
      }
      cplx acc = mkc(0.f,0.f);
      if (i < m){
        for (int cc = cc0; cc < cc1; ++cc){
          cplx a = AH[(size_t)(j+2+cc)*DN + (j+1+i)];
          cplx v = x[cc];
          acc.x += a.x*v.x - a.y*v.y;
          acc.y += a.x*v.y + a.y*v.x;
        }
        wpart[(size_t)s*DN + i] = acc;
      }
      cplx a0v = mkc(0.f,0.f);
      if (s == 0 && i < m){
        a0v = AH[(size_t)(j+1)*DN + (j+1+i)];
        a0copy[i] = a0v;
      }
      /* dp[b][s] = sum_{i>=1} conj(wpart_s[i]) x[i-1] */
      float dxx=0.f, dyy=0.f;
      if (i >= 1 && i < m){
        cplx xv = x[i-1];
        dxx = acc.x*xv.x + acc.y*xv.y;
        dyy = acc.x*xv.y - acc.y*xv.x;
      }
      __syncthreads();
      rx[t]=dxx; ry[t]=dyy; __syncthreads();
      for (int q=128;q>0;q>>=1){ if (t<q){ rx[t]+=rx[t+q]; ry[t]+=ry[t+q]; } __syncthreads(); }
      if (t==0) dp[b*CSK + s] = mkc(rx[0], ry[0]);
      if (s == 0){
        float px=0.f, py=0.f;
        if (i >= 1 && i < m){
          cplx xv = x[i-1];
          px = a0v.x*xv.x + a0v.y*xv.y;
          py = a0v.x*xv.y - a0v.y*xv.x;
        }
        __syncthreads();
        rx[t]=px; ry[t]=py; __syncthreads();
        for (int q=128;q>0;q>>=1){ if (t<q){ rx[t]+=rx[t+q]; ry[t]+=ry[t+q]; } __syncthreads(); }
        if (t==0) pa[b] = mkc(rx[0], ry[0]);
      }
    }
    gg.sync();

    /* ---- phase W: redundant finisher (parallel LDS reduce) + wvec + column scale ---- */
    {
      /* xn2 */
      __syncthreads();
      rx[t] = (t < CSK) ? ssqpart[t] : 0.f;
      __syncthreads();
      for (int q=128;q>0;q>>=1){ if (t<q) rx[t]+=rx[t+q]; __syncthreads(); }
      if (t==0) sb_[8] = rx[0];
      __syncthreads();
      /* SP over nb*CSK dp entries */
      float spx=0.f, spy=0.f;
      for (int idx=t; idx<nb*CSK; idx+=256){ cplx u = dp[idx]; spx+=u.x; spy+=u.y; }
      rx[t]=spx; ry[t]=spy; __syncthreads();
      for (int q=128;q>0;q>>=1){ if (t<q){ rx[t]+=rx[t+q]; ry[t]+=ry[t+q]; } __syncthreads(); }
      if (t==0){ sb_[9]=rx[0]; sb_[10]=ry[0]; }
      __syncthreads();
      /* SA over nb pa entries */
      rx[t] = (t<nb)? pa[t].x : 0.f; ry[t] = (t<nb)? pa[t].y : 0.f;
      __syncthreads();
      for (int q=128;q>0;q>>=1){ if (t<q){ rx[t]+=rx[t+q]; ry[t]+=ry[t+q]; } __syncthreads(); }
      if (t==0){ sb_[11]=rx[0]; sb_[12]=ry[0]; }
      __syncthreads();
      /* P0 = sum_s wpart[s][0] */
      rx[t] = (t<CSK)? wpart[(size_t)t*DN].x : 0.f;
      ry[t] = (t<CSK)? wpart[(size_t)t*DN].y : 0.f;
      __syncthreads();
      for (int q=128;q>0;q>>=1){ if (t<q){ rx[t]+=rx[t+q]; ry[t]+=ry[t+q]; } __syncthreads(); }
      if (t==0){
        float xn2 = sb_[8];
        cplx SP = mkc(sb_[9], sb_[10]);
        cplx SA = mkc(sb_[11], sb_[12]);
        cplx P0 = mkc(rx[0], ry[0]);
        cplx alpha = colr[j+1];
        if (sqrtf(xn2) == 0.f && alpha.y == 0.f){
          sb_[6] = 0.f; sb_[0]=0.f; sb_[1]=0.f; sb_[2]=0.f; sb_[3]=0.f; sb_[4]=0.f; sb_[5]=0.f;
          sb_[7] = alpha.x;
        } else {
          float beta = -copysignf(sqrtf(alpha.x*alpha.x + alpha.y*alpha.y + xn2), alpha.x);
          cplx tj = mkc((beta - alpha.x)/beta, -alpha.y/beta);
          cplx ssc = cinv(mkc(alpha.x - beta, alpha.y));
          cplx a0d = a0copy[0];
          cplx T1 = cadd(cconj(a0d), cmul(ssc, SA));
          cplx T2 = cadd(cconj(P0), cmul(ssc, SP));
          cplx dot = cmul(cconj(tj), cadd(T1, cmul(cconj(ssc), T2)));
          cplx td = cmul(tj, dot);
          sb_[0]=tj.x; sb_[1]=tj.y; sb_[2]=ssc.x; sb_[3]=ssc.y;
          sb_[4]=-0.5f*td.x; sb_[5]=-0.5f*td.y;
          sb_[6]=1.f; sb_[7]=beta;
        }
      }
      __syncthreads();
      int sdo = (sb_[6] != 0.f);
      cplx tj = mkc(sb_[0], sb_[1]);
      cplx ssc = mkc(sb_[2], sb_[3]);
      cplx al = mkc(sb_[4], sb_[5]);
      float beta = sb_[7];
      for (int i = bid*256 + t; i < m; i += G*256){
        if (sdo){
          cplx P = mkc(0.f,0.f);
          #pragma unroll 8
          for (int s=0;s<CSK;s++){ cplx u = wpart[(size_t)s*DN + i]; P.x+=u.x; P.y+=u.y; }
          cplx av = cadd(a0copy[i], cmul(ssc, P));
          cplx w1 = cmul(tj, av);
          cplx vi;
          if (i == 0){ vi = mkc(1.f,0.f); colr[j+1] = mkc(beta, 0.f); }
          else { vi = cmul(ssc, colr[j+1+i]); colr[j+1+i] = vi; }
          wvec[i] = cadd(w1, cmul(al, vi));
        } else {
          wvec[i] = mkc(0.f,0.f);
        }
      }
      if (bid == 0 && t == 0){
        if (sdo){ e[j] = beta; tauA[j] = tj; }
        else { e[j] = sb_[7]; tauA[j] = mkc(0.f,0.f); }
      }
    }
    gg.sync();

    /* ---- phase B: her2 tiles (v = scaled column, w = wvec) ---- */
    if (sb_[6] != 0.f){
      int ntr = (m+31)/32, ntc = (m+15)/16;
      const cplx* vcol = colr + (j+1);
      for (int tt = bid; tt < ntr*ntc; tt += G){
        int trb = tt % ntr, tcb = tt / ntr;
        int r = trb*32 + (t & 31);
        int cb = tcb*16 + ((t >> 5)*2);
        if (r < m){
          cplx vr = (r==0)? mkc(1.f,0.f) : vcol[r];
          cplx wr = wvec[r];
          for (int c = cb; c < cb+2; ++c){
            if (c >= m) break;
            cplx vc = (c==0)? mkc(1.f,0.f) : vcol[c];
            cplx wc = wvec[c];
            cplx u = cadd(cmul(vr, cconj(wc)), cmul(wr, cconj(vc)));
            size_t idx = (size_t)(j+1+c)*DN + (j+1+r);
            AH[idx].x -= u.x; AH[idx].y -= u.y;
          }
        }
      }
    }
    gg.sync();
  }
  /* collectD */
  for (int i = bid*256 + t; i < DN; i += G*256) d[i] = AH[(size_t)i*DN + i].x;
}

__global__ void k_zeroZ(float* Z){
  int idx = blockIdx.x*256 + threadIdx.x;
  if (idx < DN*DN) Z[idx] = 0.f;
}

/* ---------------- sstedc prep ---------------- */
__global__ void k_predc(float* d, float* e, int* indxq, Ctl* ctl){
  __shared__ float red[256];
  int t = threadIdx.x;
  float mx = 0.f;
  for (int i=t;i<DN;i+=256) mx = fmaxf(mx, fabsf(d[i]));
  for (int i=t;i<DN-1;i+=256) mx = fmaxf(mx, fabsf(e[i]));
  red[t]=mx; __syncthreads();
  for (int s=128;s>0;s>>=1){ if (t<s) red[t]=fmaxf(red[t],red[t+s]); __syncthreads(); }
  float orgnrm = red[0];
  if (t==0) ctl->orgnrm = orgnrm;
  float mul = 1.f/orgnrm;
  __syncthreads();
  for (int i=t;i<DN;i+=256) d[i]*=mul;
  for (int i=t;i<DN-1;i+=256) e[i]*=mul;
  __syncthreads();
  if (t==0){
    for (int b=1;b<NLEAVES;b++){ int s0=b*LEAF; float ae=fabsf(e[s0-1]); d[s0-1]-=ae; d[s0]-=ae; }
  }
  for (int i=t;i<DN;i+=256) indxq[i] = (i & (LEAF-1)) + 1;
}

/* ---------------- ssteqr (small, serial) ---------------- */
__device__ void slaev2_d(float a, float b, float c, float* rt1, float* rt2, float* cs1, float* sn1){
  float sm = a + c, df = a - c, adf = fabsf(df), tb = b + b, ab = fabsf(tb);
  float acmx, acmn;
  if (fabsf(a) > fabsf(c)) { acmx = a; acmn = c; } else { acmx = c; acmn = a; }
  float rt;
  if (adf > ab) rt = adf*sqrtf(1.f + (ab/adf)*(ab/adf));
  else if (adf < ab) rt = ab*sqrtf(1.f + (adf/ab)*(adf/ab));
  else rt = ab*sqrtf(2.f);
  int sgn1;
  if (sm < 0.f){ *rt1 = 0.5f*(sm - rt); sgn1 = -1; *rt2 = (acmx/(*rt1))*acmn - (b/(*rt1))*b; }
  else if (sm > 0.f){ *rt1 = 0.5f*(sm + rt); sgn1 = 1; *rt2 = (acmx/(*rt1))*acmn - (b/(*rt1))*b; }
  else { *rt1 = 0.5f*rt; *rt2 = -0.5f*rt; sgn1 = 1; }
  float cs; int sgn2;
  if (df >= 0.f){ cs = df + rt; sgn2 = 1; } else { cs = df - rt; sgn2 = -1; }
  float acs = fabsf(cs);
  if (acs > ab){ float ct = -tb/cs; *sn1 = 1.f/sqrtf(1.f + ct*ct); *cs1 = ct*(*sn1); }
  else {
    if (ab == 0.f){ *cs1 = 1.f; *sn1 = 0.f; }
    else { float tn = -cs/tb; *cs1 = 1.f/sqrtf(1.f + tn*tn); *sn1 = tn*(*cs1); }
  }
  if (sgn1 == sgn2){ float tn = *cs1; *cs1 = -(*sn1); *sn1 = tn; }
}

__device__ void slartg_d(float f, float g, float* cs, float* sn, float* r){
  if (g == 0.f){ *cs = 1.f; *sn = 0.f; *r = f; }
  else if (f == 0.f){ *cs = 0.f; *sn = copysignf(1.f, g); *r = fabsf(g); }
  else {
    float d = sqrtf(f*f + g*g);
    *cs = fabsf(f)/d;
    *r = copysignf(d, f);
    *sn = g/(*r);
  }
}

__device__ void rot1_d(float* z, int ldz, int nr, int col, float cc, float ss){
  for (int r=0;r<nr;++r){
    float tmp = z[(col+1)*ldz + r];
    z[(col+1)*ldz + r] = cc*tmp - ss*z[col*ldz + r];
    z[col*ldz + r] = ss*tmp + cc*z[col*ldz + r];
  }
}

__device__ void ssteqr_small(int n, float* d, float* e, float* z, int ldz){
  for (int c=0;c<n;c++) for (int r=0;r<n;r++) z[c*ldz+r] = (r==c)?1.f:0.f;
  const float eps=EPSF, eps2=eps*eps, safmin=SAFMINF;
  int nmaxit = n*30, jtot=0;
  int l1=0;
  float wc[LEAF], ws_[LEAF];
  while (1){
    if (l1 > n-1) break;
    if (l1 > 0) e[l1-1] = 0.f;
    int m;
    for (m = l1; m <= n-2; ++m){
      float tst = fabsf(e[m]);
      if (tst == 0.f) break;
      if (tst <= (sqrtf(fabsf(d[m]))*sqrtf(fabsf(d[m+1])))*eps){ e[m]=0.f; break; }
    }
    int l = l1, lend = m;
    l1 = m+1;
    if (lend == l) continue;
    if (fabsf(d[lend]) < fabsf(d[l])){ int tmp=l; l=lend; lend=tmp; }
    if (lend > l){
      while (1){
        int mm;
        if (l != lend){
          for (mm = l; mm <= lend-1; ++mm){
            float tst = e[mm]*e[mm];
            if (tst <= (eps2*fabsf(d[mm]))*fabsf(d[mm+1]) + safmin) break;
          }
        } else mm = lend;
        if (mm < lend) e[mm] = 0.f;
        float p = d[l];
        if (mm == l){ d[l]=p; l++; if (l<=lend) continue; else break; }
        if (mm == l+1){
          float rt1, rt2, c_, s_;
          slaev2_d(d[l], e[l], d[l+1], &rt1, &rt2, &c_, &s_);
          rot1_d(z, ldz, n, l, c_, s_);
          d[l]=rt1; d[l+1]=rt2; e[l]=0.f;
          l += 2; if (l<=lend) continue; else break;
        }
        if (jtot == nmaxit) break;
        jtot++;
        float g = (d[l+1]-p)/(2.f*e[l]);
        float rr = sqrtf(g*g+1.f);
        g = d[mm] - p + e[l]/(g + copysignf(rr, g));
        float s_ = 1.f, c_ = 1.f; p = 0.f;
        for (int i = mm-1; i >= l; --i){
          float f = s_*e[i], b = c_*e[i];
          slartg_d(g, f, &c_, &s_, &rr);
          if (i != mm-1) e[i+1] = rr;
          g = d[i+1] - p;
          rr = (d[i]-g)*s_ + 2.f*c_*b;
          p = s_*rr;
          d[i+1] = g+p;
          g = c_*rr - b;
          wc[i] = c_; ws_[i] = -s_;
        }
        for (int q = mm-1; q >= l; --q) rot1_d(z, ldz, n, q, wc[q], ws_[q]);
        d[l] = d[l] - p; e[l] = g;
      }
    } else {
      while (1){
        int mm;
        if (l != lend){
          for (mm = l; mm >= lend+1; --mm){
            float tst = e[mm-1]*e[mm-1];
            if (tst <= (eps2*fabsf(d[mm]))*fabsf(d[mm-1]) + safmin) break;
          }
        } else mm = lend;
        if (mm > lend) e[mm-1] = 0.f;
        float p = d[l];
        if (mm == l){ d[l]=p; l--; if (l>=lend) continue; else break; }
        if (mm == l-1){
          float rt1, rt2, c_, s_;
          slaev2_d(d[l-1], e[l-1], d[l], &rt1, &rt2, &c_, &s_);
          rot1_d(z, ldz, n, l-1, c_, s_);
          d[l-1]=rt1; d[l]=rt2; e[l-1]=0.f;
          l -= 2; if (l>=lend) continue; else break;
        }
        if (jtot == nmaxit) break;
        jtot++;
        float g = (d[l-1]-p)/(2.f*e[l-1]);
        float rr = sqrtf(g*g+1.f);
        g = d[mm] - p + e[l-1]/(g + copysignf(rr, g));
        float s_=1.f, c_=1.f; p=0.f;
        for (int i = mm; i <= l-1; ++i){
          float f = s_*e[i], b = c_*e[i];
          slartg_d(g, f, &c_, &s_, &rr);
          if (i != mm) e[i-1] = rr;
          g = d[i] - p;
          rr = (d[i+1]-g)*s_ + 2.f*c_*b;
          p = s_*rr;
          d[i] = g+p;
          g = c_*rr - b;
          wc[i] = c_; ws_[i] = s_;
        }
        for (int q = mm; q <= l-1; ++q) rot1_d(z, ldz, n, q, wc[q], ws_[q]);
        d[l] = d[l]-p; e[l-1] = g;
      }
    }
  }
  for (int ii=1; ii<n; ++ii){
    int i = ii-1, k = i; float pp = d[i];
    for (int jj=ii; jj<n; ++jj) if (d[jj] < pp){ k=jj; pp=d[jj]; }
    if (k != i){
      d[k]=d[i]; d[i]=pp;
      for (int r=0;r<n;r++){ float tv=z[i*ldz+r]; z[i*ldz+r]=z[k*ldz+r]; z[k*ldz+r]=tv; }
    }
  }
}

__global__ void k_leaves(float* d, float* e, float* Zmat){
  __shared__ float sd[LEAF], se[LEAF], sz[LEAF*LEAF];
  int off = blockIdx.x*LEAF;
  int t = threadIdx.x;
  if (t < LEAF){ sd[t] = d[off+t]; se[t] = (t<LEAF-1)? e[off+t] : 0.f; }
  __syncthreads();
  if (t==0) ssteqr_small(LEAF, sd, se, sz, LEAF);
  __syncthreads();
  if (t < LEAF){ d[off+t]=sd[t]; if (t<LEAF-1) e[off+t]=se[t]; }
  for (int i=t; i<LEAF*LEAF; i+=64){
    int c = i/LEAF, r = i%LEAF;
    Zmat[(size_t)(off+c)*DN + (off+r)] = sz[c*LEAF+r];
  }
}

/* ---------------- BATCHED merge prep: one block per merge, LDS-resident scan ---------------- */
__global__ void __launch_bounds__(256) k_mprep_b(
    float* d, const float* e, const float* Zmat, int* indxq,
    float* dlamda_g, float* wkeep_g, int* indx_g, int* indxc_g,
    float* rotc, float* rots, int* rotp, int* rotn,
    Ctl* ctls, int n)
{
  __shared__ float sz[2048];
  __shared__ float sdl[2048];
  __shared__ float sA[2048];
  __shared__ int   sB[2048];
  __shared__ int   sixl[2048];
  __shared__ int   sixp[2048];
  __shared__ int   sctp[2048];
  __shared__ float red[256];
  __shared__ float s_mz, s_md;
  int q = blockIdx.x;
  int off = q*n;
  int n1 = n/2, n2 = n - n1;
  Ctl* ctl = ctls + q;
  int t = threadIdx.x;
  float rho0 = e[off + n1 - 1];
  for (int c = t; c < n; c += 256){
    float val = (c < n1) ? Zmat[(size_t)(off+c)*DN + (off+n1-1)]
                         : Zmat[(size_t)(off+c)*DN + (off+n1)];
    if (c >= n1){ if (rho0 < 0.f) val = -val; indxq[off+c] += n1; }
    sz[c] = val * 0.70710678118654752440f;
    sdl[c] = d[off+c];
  }
  __syncthreads();
  for (int i = t; i < n; i += 256) sA[i] = sdl[indxq[off+i] - 1];
  __syncthreads();
  if (t == 0){
    int i1=0, i2=n1, ns1=n1, ns2=n2, k=0;
    while (ns1>0 && ns2>0){
      if (sA[i1] <= sA[i2]){ sB[k++]=i1+1; i1++; ns1--; }
      else { sB[k++]=i2+1; i2++; ns2--; }
    }
    while (ns1>0){ sB[k++]=i1+1; i1++; ns1--; }
    while (ns2>0){ sB[k++]=i2+1; i2++; ns2--; }
  }
  __syncthreads();
  for (int i = t; i < n; i += 256) sixl[i] = indxq[off + sB[i] - 1] - 1;
  __syncthreads();
  float mz=0.f, md=0.f;
  for (int i=t;i<n;i+=256){ mz = fmaxf(mz, fabsf(sz[i])); md = fmaxf(md, fabsf(sdl[i])); }
  red[t]=mz; __syncthreads();
  for (int s=128;s>0;s>>=1){ if (t<s) red[t]=fmaxf(red[t],red[t+s]); __syncthreads(); }
  if (t==0) s_mz = red[0];
  __syncthreads();
  red[t]=md; __syncthreads();
  for (int s=128;s>0;s>>=1){ if (t<s) red[t]=fmaxf(red[t],red[t+s]); __syncthreads(); }
  if (t==0) s_md = red[0];
  __syncthreads();
  if (t == 0){
    float rho = fabsf(2.f*rho0);
    float tol = 8.f*EPSF*fmaxf(s_md, s_mz);
    ctl->rho = rho;
    if (rho*s_mz <= tol){
      ctl->K = 0; ctl->nrot = 0;
      ctl->ctot[0]=0; ctl->ctot[1]=0; ctl->ctot[2]=0; ctl->ctot[3]=n;
      ctl->n12 = 0; ctl->n23 = 0;
    } else {
      for (int i=0;i<n1;i++) sctp[i]=0;
      for (int i=n1;i<n;i++) sctp[i]=2;
      int K=0, k2=n, nrot=0, pj=0;
      int jj=0;
      for (; jj<n; ++jj){
        int nj = sixl[jj];
        if (rho*fabsf(sz[nj]) <= tol){ k2--; sctp[nj]=3; sixp[k2]=nj; }
        else { pj = nj; break; }
      }
      for (;;){
        jj++;
        if (jj >= n) break;
        int nj = sixl[jj];
        if (rho*fabsf(sz[nj]) <= tol){ k2--; sctp[nj]=3; sixp[k2]=nj; }
        else {
          float s_ = sz[pj], c_ = sz[nj];
          float tau_ = sqrtf(c_*c_ + s_*s_);
          float tt = sdl[nj] - sdl[pj];
          c_ = c_/tau_; s_ = -s_/tau_;
          if (fabsf(tt*c_*s_) <= tol){
            sz[nj] = tau_; sz[pj] = 0.f;
            if (sctp[nj] != sctp[pj]) sctp[nj] = 1;
            sctp[pj] = 3;
            rotp[off+nrot]=pj; rotn[off+nrot]=nj; rotc[off+nrot]=c_; rots[off+nrot]=s_; nrot++;
            float t2 = sdl[pj]*c_*c_ + sdl[nj]*s_*s_;
            sdl[nj] = sdl[pj]*s_*s_ + sdl[nj]*c_*c_;
            sdl[pj] = t2;
            k2--;
            int ii = 1;
            for (;;){
              if (k2+ii <= n-1){
                if (sdl[pj] < sdl[sixp[k2+ii]]){ sixp[k2+ii-1]=sixp[k2+ii]; sixp[k2+ii]=pj; ii++; }
                else { sixp[k2+ii-1]=pj; break; }
              } else { sixp[k2+ii-1]=pj; break; }
            }
            pj = nj;
          } else {
            dlamda_g[off+K]=sdl[pj]; wkeep_g[off+K]=sz[pj]; sixp[K]=pj; K++;
            pj = nj;
          }
        }
      }
      dlamda_g[off+K]=sdl[pj]; wkeep_g[off+K]=sz[pj]; sixp[K]=pj; K++;
      int ct[4]={0,0,0,0};
      for (int q2=0;q2<n;q2++) ct[sctp[q2]]++;
      int psm[4]; psm[0]=0; psm[1]=ct[0]; psm[2]=ct[0]+ct[1]; psm[3]=ct[0]+ct[1]+ct[2];
      for (int q2=0;q2<n;q2++){
        int js = sixp[q2]; int cc = sctp[js];
        sixl[psm[cc]] = js; sB[psm[cc]] = q2; psm[cc]++;
      }
      ctl->K = K; ctl->nrot = nrot;
      ctl->ctot[0]=ct[0]; ctl->ctot[1]=ct[1]; ctl->ctot[2]=ct[2]; ctl->ctot[3]=ct[3];
      ctl->n12 = ct[0]+ct[1]; ctl->n23 = ct[1]+ct[2];
    }
  }
  __syncthreads();
  for (int i=t;i<n;i+=256){
    d[off+i] = sdl[i];
    indx_g[off+i] = sixl[i];
    indxc_g[off+i] = sB[i];
  }
}

__global__ void k_mrot_b(float* Zmat, const float* rotc, const float* rots,
                         const int* rotp, const int* rotn, const Ctl* ctls, int n){
  int q = blockIdx.y;
  int off = q*n;
  int r = blockIdx.x*256 + threadIdx.x;
  if (r >= n) return;
  int nrot = ctls[q].nrot;
  for (int p=0;p<nrot;++p){
    size_t ip = (size_t)(off+rotp[off+p])*DN + off + r;
    size_t in_ = (size_t)(off+rotn[off+p])*DN + off + r;
    float x = Zmat[ip], y = Zmat[in_];
    float cc = rotc[off+p], ss = rots[off+p];
    Zmat[ip]  = cc*x + ss*y;
    Zmat[in_] = cc*y - ss*x;
  }
}

__global__ void k_mcopyA_b(const float* d, const float* Zmat, float* Q2g, float* dgrp,
                           const int* indx, const Ctl* ctls, int n){
  int q = blockIdx.y;
  int off = q*n;
  int p = blockIdx.x;
  int t = threadIdx.x;
  int n1 = n/2, n2 = n - n1;
  const Ctl* ctl = ctls + q;
  float* Q2 = Q2g + (size_t)off*n;
  int c0 = ctl->ctot[0], c1 = ctl->ctot[1], c2 = ctl->ctot[2];
  int K = c0+c1+c2;
  int src = indx[off+p];
  const float* qcol = Zmat + (size_t)(off+src)*DN + off;
  if (t == 0) dgrp[off+p] = d[off+src];
  size_t base2 = (size_t)n1*(c0+c1);
  size_t base3 = base2 + (size_t)n2*(c1+c2);
  if (p < c0){
    float* dst = Q2 + (size_t)p*n1;
    for (int r=t;r<n1;r+=256) dst[r] = qcol[r];
  } else if (p < c0+c1){
    float* d1 = Q2 + (size_t)p*n1;
    float* d2 = Q2 + base2 + (size_t)(p-c0)*n2;
    for (int r=t;r<n1;r+=256) d1[r] = qcol[r];
    for (int r=t;r<n2;r+=256) d2[r] = qcol[n1+r];
  } else if (p < K){
    float* d2 = Q2 + base2 + (size_t)(p-c0)*n2;
    for (int r=t;r<n2;r+=256) d2[r] = qcol[n1+r];
  } else {
    float* dst = Q2 + base3 + (size_t)(p-K)*n;
    for (int r=t;r<n;r+=256) dst[r] = qcol[r];
  }
}

__global__ void k_mcopyB_b(float* d, float* Zmat, const float* Q2g, const float* dgrp,
                           const Ctl* ctls, int n){
  int q = blockIdx.y;
  int off = q*n;
  int p = blockIdx.x;
  int t = threadIdx.x;
  int n1 = n/2, n2 = n - n1;
  const Ctl* ctl = ctls + q;
  const float* Q2 = Q2g + (size_t)off*n;
  int c0 = ctl->ctot[0], c1 = ctl->ctot[1], c2 = ctl->ctot[2];
  int K = c0+c1+c2;
  if (p < K) return;
  size_t base3 = (size_t)n1*(c0+c1) + (size_t)n2*(c1+c2);
  const float* src = Q2 + base3 + (size_t)(p-K)*n;
  float* dst = Zmat + (size_t)(off+p)*DN + off;
  for (int r=t;r<n;r+=256) dst[r] = src[r];
  if (t==0) d[off+p] = dgrp[off+p];
}

__global__ void k_msec_b(float* d, float* Zmat, const float* dl_g, const float* w_g,
                         const Ctl* ctls, int n){
  int q = blockIdx.y;
  int off = q*n;
  int j = blockIdx.x*64 + threadIdx.x;
  int K = ctls[q].K;
  if (j >= K) return;
  float rho = ctls[q].rho;
  const float* dl = dl_g + off;
  const float* w = w_g + off;
  float* delta = Zmat + (size_t)(off+j)*DN + off;
  if (K == 1){
    d[off] = dl[0] + rho*w[0]*w[0];
    delta[0] = 1.f;
    return;
  }
  int orig; float lo, hi;
  if (j < K-1){
    float gap = dl[j+1] - dl[j];
    float half = 0.5f*gap;
    float fmid = 1.f;
    for (int l=0;l<K;l++){
      float D = (dl[l]-dl[j]) - half;
      fmid += rho*w[l]*w[l]/D;
    }
    if (fmid >= 0.f){ orig = j;   lo = 0.f;   hi = half; }
    else            { orig = j+1; lo = -half; hi = 0.f;  }
  } else {
    float s2 = 0.f;
    for (int l=0;l<K;l++) s2 += w[l]*w[l];
    orig = K-1; lo = 0.f; hi = rho*s2*1.000002f + 1e-30f;
  }
  float dorig = dl[orig];
  float eta = 0.5f*(lo+hi);
  for (int it=0; it<50; ++it){
    float g = 1.f, gp = 0.f;
    for (int l=0;l<K;l++){
      float del = (dl[l]-dorig) - eta;
      float r = w[l]/del;
      g  += rho*w[l]*r;
      gp += rho*r*r;
    }
    if (g > 0.f) hi = eta; else lo = eta;
    float etan = eta - g/gp;
    if (!(etan > lo && etan < hi)) etan = 0.5f*(lo+hi);
    if (etan == eta) break;
    eta = etan;
  }
  d[off+j] = dorig + eta;
  for (int l=0;l<K;l++) delta[l] = (dl[l]-dorig) - eta;
}

__global__ void k_mzhat_b(const float* dl_g, const float* w_g, float* what,
                          const float* Zmat, const Ctl* ctls, int n){
  int q = blockIdx.y;
  int off = q*n;
  int K = ctls[q].K;
  int i = blockIdx.x*64 + threadIdx.x;
  if (i >= K) return;
  const float* dlamda = dl_g + off;
  float acc = Zmat[(size_t)(off+i)*DN + off+i];
  float di = dlamda[i];
  for (int jj=0;jj<K;jj++){
    if (jj==i) continue;
    acc *= Zmat[(size_t)(off+jj)*DN + off+i] / (di - dlamda[jj]);
  }
  what[off+i] = copysignf(sqrtf(fabsf(acc)), w_g[off+i]);
}

__global__ void k_mvec_b(float* Zmat, const float* what, const int* indxc,
                         const Ctl* ctls, int n){
  __shared__ float sv[2048];
  __shared__ float red[256];
  int q = blockIdx.y;
  int off = q*n;
  int K = ctls[q].K;
  int j = blockIdx.x;
  if (j >= K) return;
  int t = threadIdx.x;
  float* col = Zmat + (size_t)(off+j)*DN + off;
  float ssq = 0.f;
  for (int i=t;i<K;i+=256){
    float den = col[i];
    if (den == 0.f) den = 1e-30f;
    float v = what[off+i]/den; sv[i]=v; ssq += v*v;
  }
  red[t]=ssq; __syncthreads();
  for (int s=128;s>0;s>>=1){ if (t<s) red[t]+=red[t+s]; __syncthreads(); }
  float temp = sqrtf(red[0]);
  for (int i=t;i<K;i+=256) col[i] = sv[indxc[off+i]]/temp;
}

__global__ void k_mcopyS_b(float* Smatg, const float* Zmat, const Ctl* ctls, int n, int mode){
  int q = blockIdx.y;
  int off = q*n;
  const Ctl* ctl = ctls + q;
  int K = ctl->K; if (K==0) return;
  int rows = (mode==1)? ctl->n23 : ctl->n12;
  int rowoff = (mode==1)? ctl->ctot[0] : 0;
  if (rows==0) return;
  float* Smat = Smatg + (size_t)off*n;
  size_t tot = (size_t)rows*K;
  for (size_t idx = (size_t)blockIdx.x*256+threadIdx.x; idx < tot; idx += (size_t)gridDim.x*256){
    int r = (int)(idx % rows); int c = (int)(idx / rows);
    Smat[idx] = Zmat[(size_t)(off+c)*DN + off + rowoff + r];
  }
}

__global__ void k_sgemm_dc64_b(float* Zmat, const float* Q2g, const float* Smatg,
                               const Ctl* ctls, int n, int mode){
  int q = blockIdx.z;
  int off = q*n;
  const Ctl* ctl = ctls + q;
  int K = ctl->K; if (K==0) return;
  int n1 = n/2, n2 = n-n1;
  const float* Q2 = Q2g + (size_t)off*n;
  const float* Smat = Smatg + (size_t)off*n;
  int m, kd; const float* A; int lda; float* C;
  if (mode==1){ m=n2; kd=ctl->n23; A = Q2 + (size_t)n1*ctl->n12; lda=n2; C = Zmat + (size_t)off*DN + off+n1; }
  else { m=n1; kd=ctl->n12; A = Q2; lda=n1; C = Zmat + (size_t)off*DN + off; }
  int tr = blockIdx.x*64, tc = blockIdx.y*64;
  if (tr >= m || tc >= K) return;
  __shared__ float As[64][17], Bs[16][65];
  int tid = threadIdx.x, tx = tid & 15, ty = tid >> 4;
  float acc[4][4];
  #pragma unroll
  for (int i=0;i<4;i++) for (int jq=0;jq<4;jq++) acc[i][jq]=0.f;
  for (int k0=0;k0<kd;k0+=16){
    #pragma unroll
    for (int p=0;p<4;p++){
      int r = tid & 63, kk = (tid >> 6) + 4*p;
      As[r][kk] = (tr+r<m && k0+kk<kd) ? A[(size_t)(k0+kk)*lda + tr+r] : 0.f;
    }
    #pragma unroll
    for (int p=0;p<4;p++){
      int kk = tid & 15, c = (tid >> 4) + 16*p;
      Bs[kk][c] = (k0+kk<kd && tc+c<K) ? Smat[(size_t)(tc+c)*kd + k0+kk] : 0.f;
    }
    __syncthreads();
    #pragma unroll
    for (int k=0;k<16;k++){
      float a[4], b[4];
      #pragma unroll
      for (int i=0;i<4;i++){ a[i]=As[tx+16*i][k]; b[i]=Bs[k][ty+16*i]; }
      #pragma unroll
      for (int i=0;i<4;i++)
        #pragma unroll
        for (int jq=0;jq<4;jq++) acc[i][jq] += a[i]*b[jq];
    }
    __syncthreads();
  }
  #pragma unroll
  for (int i=0;i<4;i++)
    #pragma unroll
    for (int jq=0;jq<4;jq++){
      int r = tr+tx+16*i, c = tc+ty+16*jq;
      if (r < m && c < K) C[(size_t)c*DN + r] = acc[i][jq];
    }
}

__global__ void k_mmerge_b(float* d, int* indxq, const Ctl* ctls, int n){
  int q = blockIdx.x;
  int off = q*n;
  int K = ctls[q].K;
  if (K == 0){ for (int i=0;i<n;i++) indxq[off+i]=i+1; return; }
  int i1=0, i2=n-1, ns1=K, ns2=n-K, k=0;
  while (ns1>0 && ns2>0){
    if (d[off+i1] <= d[off+i2]){ indxq[off+k++]=i1+1; i1++; ns1--; }
    else { indxq[off+k++]=i2+1; i2--; ns2--; }
  }
  while (ns1>0){ indxq[off+k++]=i1+1; i1++; ns1--; }
  while (ns2>0){ indxq[off+k++]=i2+1; i2--; ns2--; }
}

/* ---------------- final permutation + scale back ---------------- */
__global__ void k_fpermA(const float* d, const float* Zmat, float* Q2, float* dtmp, const int* indxq){
  int i = blockIdx.x; int t = threadIdx.x;
  int src = indxq[i]-1;
  if (t==0) dtmp[i] = d[src];
  const float* sc = Zmat + (size_t)src*DN;
  float* dc = Q2 + (size_t)i*DN;
  for (int r=t;r<DN;r+=256) dc[r]=sc[r];
}
__global__ void k_fpermB(float* evals, float* Zmat, const float* Q2, const float* dtmp, const Ctl* ctl){
  int i = blockIdx.x; int t = threadIdx.x;
  if (t==0) evals[i] = dtmp[i]*ctl->orgnrm;
  const float* sc = Q2 + (size_t)i*DN;
  float* dc = Zmat + (size_t)i*DN;
  for (int r=t;r<DN;r+=256) dc[r]=sc[r];
}

/* ---------------- cunmqr on split re/im planes ---------------- */
__global__ void k_packV(const cplx* AH, cplx* Vp, int i0, int ib, int m){
  int idx = blockIdx.x*256 + threadIdx.x;
  if (idx >= m*ib) return;
  int r = idx % m, c = idx / m;
  int grow = i0+1+r, pc = i0+c+1;
  cplx v;
  if (grow < pc) v = mkc(0.f,0.f);
  else if (grow == pc) v = mkc(1.f,0.f);
  else v = AH[(size_t)(i0+c)*DN + grow];
  Vp[(size_t)c*m + r] = v;
}

/* one block per (r,c) pair */
__global__ void k_vhv2(const cplx* Vp, cplx* vhv, int m, int ib){
  __shared__ float rx[256], ry[256];
  int r = blockIdx.x, c = blockIdx.y;
  if (r >= c || c >= ib) return;
  int t = threadIdx.x;
  float dx=0.f, dy=0.f;
  for (int rl=c+t; rl<m; rl+=256){
    cplx a = Vp[(size_t)r*m + rl];
    cplx b = Vp[(size_t)c*m + rl];
    dx += a.x*b.x + a.y*b.y;
    dy += a.x*b.y - a.y*b.x;
  }
  rx[t]=dx; ry[t]=dy; __syncthreads();
  for (int s=128;s>0;s>>=1){ if (t<s){ rx[t]+=rx[t+s]; ry[t]+=ry[t+s]; } __syncthreads(); }
  if (t==0) vhv[r + c*NB] = mkc(rx[0], ry[0]);
}

__global__ void k_bldT(const cplx* vhv, const cplx* tau, cplx* T, int ib){
  int t = threadIdx.x;
  for (int idx=t; idx<NB*NB; idx+=64) T[idx] = mkc(0.f,0.f);
  __syncthreads();
  for (int c=0; c<ib; ++c){
    if (t < c){
      cplx acc = mkc(0.f,0.f);
      for (int q=t; q<c; ++q) acc = cadd(acc, cmul(T[t + q*NB], vhv[q + c*NB]));
      cplx nt = mkc(-tau[c].x, -tau[c].y);
      T[t + c*NB] = cmul(nt, acc);
    }
    if (t == c) T[c + c*NB] = tau[c];
    __syncthreads();
  }
}

__global__ void k_cgemm_ct64(const cplx* A, const float* Cre, const float* Cim,
                             cplx* G1, int row0, int m, int ib, int ksz){
  int tc = blockIdx.y*64;
  int s = blockIdx.z;
  int ks0 = s*ksz, ks1 = ks0 + ksz; if (ks1 > m) ks1 = m;
  __shared__ cplx As[64][17], Bs[16][65];
  int tid = threadIdx.x, tx = tid & 15, ty = tid >> 4;
  cplx acc[4][4];
  #pragma unroll
  for (int i=0;i<4;i++) for (int jq=0;jq<4;jq++) acc[i][jq]=mkc(0.f,0.f);
  for (int k0 = ks0; k0 < ks1; k0 += 16){
    #pragma unroll
    for (int p=0;p<4;p++){
      int kk = tid & 15, r = (tid >> 4) + 16*p;
      cplx v = mkc(0.f,0.f);
      if (r < ib && k0+kk < ks1) v = cconj(A[(size_t)r*m + k0+kk]);
      As[r][kk] = v;
    }
    #pragma unroll
    for (int p=0;p<4;p++){
      int kk = tid & 15, c = (tid >> 4) + 16*p;
      cplx v = mkc(0.f,0.f);
      int kg = k0+kk, cg = tc+c;
      if (kg < ks1 && cg < DN){ size_t bi = (size_t)cg*DN + row0 + kg; v = mkc(Cre[bi], Cim[bi]); }
      Bs[kk][c] = v;
    }
    __syncthreads();
    #pragma unroll
    for (int k=0;k<16;k++){
      cplx a[4], b[4];
      #pragma unroll
      for (int i=0;i<4;i++){ a[i]=As[tx+16*i][k]; b[i]=Bs[k][ty+16*i]; }
      #pragma unroll
      for (int i=0;i<4;i++)
        #pragma unroll
        for (int jq=0;jq<4;jq++){
          acc[i][jq].x += a[i].x*b[jq].x - a[i].y*b[jq].y;
          acc[i][jq].y += a[i].x*b[jq].y + a[i].y*b[jq].x;
        }
    }
    __syncthreads();
  }
  #pragma unroll
  for (int i=0;i<4;i++)
    #pragma unroll
    for (int jq=0;jq<4;jq++){
      int r = tx+16*i, c = tc+ty+16*jq;
      if (r < ib && c < DN) G1[(size_t)s*NB*DN + r + (size_t)c*NB] = acc[i][jq];
    }
}

__global__ void k_cgemm_nn(const cplx* A, int lda, const cplx* B, int ldb,
                           cplx* C, int ldc, int m, int nn, int kk, int S, int ssz){
  __shared__ cplx As[32][33], Bs[32][33];
  int tr = blockIdx.x*32, tc = blockIdx.y*32;
  if (tr >= m || tc >= nn) return;
  int tx = threadIdx.x & 31, ty = threadIdx.x >> 5;
  cplx acc[4]; for (int q=0;q<4;q++) acc[q]=mkc(0.f,0.f);
  for (int k0=0;k0<kk;k0+=32){
    for (int q=0;q<4;q++){ int kc=k0+ty+q*8; int r=tr+tx;
      As[tx][ty+q*8] = (r<m && kc<kk)? A[(size_t)kc*lda + r] : mkc(0.f,0.f); }
    for (int q=0;q<4;q++){ int cc=tc+ty+q*8; int kr=k0+tx;
      cplx v = mkc(0.f,0.f);
      if (kr<kk && cc<nn){
        for (int s=0;s<S;s++){ cplx u = B[(size_t)s*ssz + kr + (size_t)cc*ldb]; v.x+=u.x; v.y+=u.y; }
      }
      Bs[tx][ty+q*8] = v; }
    __syncthreads();
    for (int kq=0;kq<32;kq++){
      cplx a = As[tx][kq];
      #pragma unroll
      for (int q=0;q<4;q++){
        cplx b = Bs[kq][ty+q*8];
        acc[q].x += a.x*b.x - a.y*b.y;
        acc[q].y += a.x*b.y + a.y*b.x;
      }
    }
    __syncthreads();
  }
  int r = tr+tx;
  if (r < m){
    for (int q=0;q<4;q++){ int c = tc+ty+q*8; if (c < nn) C[r + (size_t)c*NB] = acc[q]; }
  }
}

__global__ void k_cupdate64(const cplx* A, const cplx* G2, float* Cre, float* Cim,
                            int row0, int m, int ib){
  int tr = blockIdx.x*64, tc = blockIdx.y*64;
  if (tr >= m) return;
  __shared__ cplx As[64][17], Bs[16][65];
  int tid = threadIdx.x, tx = tid & 15, ty = tid >> 4;
  cplx acc[4][4];
  #pragma unroll
  for (int i=0;i<4;i++) for (int jq=0;jq<4;jq++) acc[i][jq]=mkc(0.f,0.f);
  for (int k0=0;k0<ib;k0+=16){
    #pragma unroll
    for (int p=0;p<4;p++){
      int r = tid & 63, kk = (tid >> 6) + 4*p;
      As[r][kk] = (tr+r<m && k0+kk<ib)? A[(size_t)(k0+kk)*m + tr+r] : mkc(0.f,0.f);
    }
    #pragma unroll
    for (int p=0;p<4;p++){
      int kk = tid & 15, c = (tid >> 4) + 16*p;
      Bs[kk][c] = (k0+kk<ib && tc+c<DN)? G2[(k0+kk) + (size_t)(tc+c)*NB] : mkc(0.f,0.f);
    }
    __syncthreads();
    #pragma unroll
    for (int k=0;k<16;k++){
      cplx a[4], b[4];
      #pragma unroll
      for (int i=0;i<4;i++){ a[i]=As[tx+16*i][k]; b[i]=Bs[k][ty+16*i]; }
      #pragma unroll
      for (int i=0;i<4;i++)
        #pragma unroll
        for (int jq=0;jq<4;jq++){
          acc[i][jq].x += a[i].x*b[jq].x - a[i].y*b[jq].y;
          acc[i][jq].y += a[i].x*b[jq].y + a[i].y*b[jq].x;
        }
    }
    __syncthreads();
  }
  #pragma unroll
  for (int i=0;i<4;i++)
    #pragma unroll
    for (int jq=0;jq<4;jq++){
      int r = tr+tx+16*i, c = tc+ty+16*jq;
      if (r < m && c < DN){
        size_t idx = (size_t)c*DN + row0 + r;
        Cre[idx] -= acc[i][jq].x;
        Cim[idx] -= acc[i][jq].y;
      }
    }
}

/* ---------------- outputs (real parts only) ---------------- */
__global__ void k_outVre_t(const float* Cre, float* out0){
  __shared__ float tile[32][33];
  int C0 = blockIdx.x*32, R0 = blockIdx.y*32;
  int tx = threadIdx.x & 31, ty = threadIdx.x >> 5;
  for (int p=0;p<4;p++){
    int cy = ty + 8*p;
    tile[cy][tx] = Cre[(size_t)(C0+cy)*DN + R0+tx];
  }
  __syncthreads();
  for (int p=0;p<4;p++){
    int ry = ty + 8*p;
    out0[(size_t)(R0+ry)*DN + C0+tx] = tile[tx][ry];
  }
}
__global__ void k_outVinv(const float* Cre, float* out1){
  int idx = blockIdx.x*256 + threadIdx.x;
  if (idx >= DN*DN) return;
  out1[idx] = Cre[idx];
}
__global__ void k_outEvo(const float* evals, const float* dt, float* out2, int T){
  int idx = blockIdx.x*256 + threadIdx.x;
  if (idx >= T*DN) return;
  int k = idx & (DN-1), tt = idx >> 11;
  out2[idx] = cosf(evals[k]*dt[tt]);
}

/* ---------------- host ---------------- */
extern "C" void kernel_launch(void* const* d_in, const int* in_sizes, int n_in,
                              void* d_out, int out_size, void* d_ws, size_t ws_size,
                              hipStream_t stream)
{
  const float* sk = (const float*)d_in[0];
  const float* dt = (const float*)d_in[1];
  int Ttot = in_sizes[1];
  float* out = (float*)d_out;
  (void)n_in; (void)out_size;

  const size_t N2 = (size_t)DN*DN;
  cplx*  AH   = (cplx*)out;
  float* Smat = out + 2*N2;
  float* Zmat = (float*)d_ws;           /* = Cre */
  float* Q2   = (float*)d_ws + N2;      /* = Cim */
  float* Cre  = Zmat;
  float* Cim  = Q2;

  char* wp = (char*)d_ws + 2*N2*sizeof(float);
  auto carve = [&](size_t b)->void*{ void* p=(void*)wp; wp += (b+255)&~(size_t)255; return p; };
  float* dd     = (float*)carve(DN*sizeof(float));
  float* ee     = (float*)carve(DN*sizeof(float));
  float* dtmp   = (float*)carve(DN*sizeof(float));
  float* dlamda = (float*)carve(DN*sizeof(float));
  float* wkeep  = (float*)carve(DN*sizeof(float));
  float* what   = (float*)carve(DN*sizeof(float));
  float* dgrp   = (float*)carve(DN*sizeof(float));
  float* rotc   = (float*)carve(DN*sizeof(float));
  float* rots   = (float*)carve(DN*sizeof(float));
  float* evals  = (float*)carve(DN*sizeof(float));
  float* ssqpart= (float*)carve(CSK*sizeof(float));
  cplx*  tauA   = (cplx*)carve(DN*sizeof(cplx));
  cplx*  a0copy = (cplx*)carve(DN*sizeof(cplx));
  cplx*  wvecA  = (cplx*)carve(DN*sizeof(cplx));
  cplx*  dp     = (cplx*)carve(8*CSK*sizeof(cplx));
  cplx*  pa     = (cplx*)carve(64*sizeof(cplx));
  int*   indxq  = (int*)carve(DN*sizeof(int));
  int*   indx   = (int*)carve(DN*sizeof(int));
  int*   indxc  = (int*)carve(DN*sizeof(int));
  int*   rotp   = (int*)carve(DN*sizeof(int));
  int*   rotn   = (int*)carve(DN*sizeof(int));
  Ctl*   ctlG   = (Ctl*)carve(sizeof(Ctl));
  Ctl*   ctls   = (Ctl*)carve(NLEAVES*sizeof(Ctl));
  cplx*  Vp     = (cplx*)carve((size_t)DN*NB*sizeof(cplx));   /* 1 MB; wpart [CSK][DN] aliases */
  cplx*  G2     = (cplx*)carve((size_t)NB*DN*sizeof(cplx));
  cplx*  Tm     = (cplx*)carve((size_t)NB*NB*sizeof(cplx));
  cplx*  vhv    = (cplx*)carve((size_t)NB*NB*sizeof(cplx));
  size_t used = (size_t)(wp - (char*)d_ws);
  int S = 8;
  while (S > 1 && (ws_size != 0) && (used + (size_t)S*NB*DN*sizeof(cplx) > ws_size)) S >>= 1;
  if (ws_size == 0) S = 1;
  cplx*  G1     = (cplx*)carve((size_t)S*NB*DN*sizeof(cplx));
  cplx*  wpart  = Vp;

  /* 1. build H */
  {
    dim3 gb(DN/32, DN/32);
    k_buildH_t<<<gb,256,0,stream>>>(sk, AH);
  }

  /* 2. chetd2: single persistent cooperative kernel */
  {
    void* kargs[] = { (void*)&AH, (void*)&wpart, (void*)&ssqpart, (void*)&dp, (void*)&pa,
                      (void*)&a0copy, (void*)&wvecA, (void*)&tauA, (void*)&ee, (void*)&dd };
    hipLaunchCooperativeKernel((void*)k_chetd2, dim3(GBLK), dim3(256), kargs, 0, stream);
  }

  /* 3. sstedc('I') equivalent (real D&C, level-batched) */
  k_zeroZ<<<(DN*DN+255)/256,256,0,stream>>>(Zmat);
  k_predc<<<1,256,0,stream>>>(dd, ee, indxq, ctlG);
  k_leaves<<<NLEAVES,64,0,stream>>>(dd, ee, Zmat);

  for (int szv = LEAF; szv < DN; szv *= 2){
    int n = 2*szv;
    int M = DN/n;
    k_mprep_b<<<M,256,0,stream>>>(dd, ee, Zmat, indxq, dlamda, wkeep, indx, indxc,
                                  rotc, rots, rotp, rotn, ctls, n);
    k_mrot_b<<<dim3((n+255)/256, M),256,0,stream>>>(Zmat, rotc, rots, rotp, rotn, ctls, n);
    k_mcopyA_b<<<dim3(n, M),256,0,stream>>>(dd, Zmat, Q2, dgrp, indx, ctls, n);
    k_mcopyB_b<<<dim3(n, M),256,0,stream>>>(dd, Zmat, Q2, dgrp, ctls, n);
    k_msec_b<<<dim3((n+63)/64, M),64,0,stream>>>(dd, Zmat, dlamda, wkeep, ctls, n);
    k_mzhat_b<<<dim3((n+63)/64, M),64,0,stream>>>(dlamda, wkeep, what, Zmat, ctls, n);
    k_mvec_b<<<dim3(n, M),256,0,stream>>>(Zmat, what, indxc, ctls, n);
    int gcs = ((n*n)+255)/256; if (gcs > 4096) gcs = 4096;
    k_mcopyS_b<<<dim3(gcs, M),256,0,stream>>>(Smat, Zmat, ctls, n, 1);
    dim3 gg((n+63)/64,(n+63)/64,M);
    k_sgemm_dc64_b<<<gg,256,0,stream>>>(Zmat, Q2, Smat, ctls, n, 1);
    k_mcopyS_b<<<dim3(gcs, M),256,0,stream>>>(Smat, Zmat, ctls, n, 2);
    k_sgemm_dc64_b<<<gg,256,0,stream>>>(Zmat, Q2, Smat, ctls, n, 2);
    k_mmerge_b<<<M,1,0,stream>>>(dd, indxq, ctls, n);
  }
  k_fpermA<<<DN,256,0,stream>>>(dd, Zmat, Q2, dtmp, indxq);
  k_fpermB<<<DN,256,0,stream>>>(evals, Zmat, Q2, dtmp, ctlG);

  /* evo output (Smat region dead; evals in d_ws) */
  k_outEvo<<<((Ttot*DN)+255)/256,256,0,stream>>>(evals, dt, out + 2*N2, Ttot);

  /* 4. cunmqr on split planes: Cre = Zmat (in place), Cim = 0 */
  k_zeroZ<<<(DN*DN+255)/256,256,0,stream>>>(Cim);
  int Krefl = DN-1;
  for (int i0 = ((Krefl-1)/NB)*NB; i0 >= 0; i0 -= NB){
    int ib = Krefl - i0; if (ib > NB) ib = NB;
    int m = DN-1-i0;
    int row0 = i0+1;
    k_packV<<<((m*ib)+255)/256,256,0,stream>>>(AH, Vp, i0, ib, m);
    dim3 gvh(ib, ib);
    k_vhv2<<<gvh,256,0,stream>>>(Vp, vhv, m, ib);
    k_bldT<<<1,64,0,stream>>>(vhv, tauA+i0, Tm, ib);
    int ksz = ((m + S - 1)/S + 15) & ~15;
    dim3 gct(1, DN/64, S);
    k_cgemm_ct64<<<gct,256,0,stream>>>(Vp, Cre, Cim, G1, row0, m, ib, ksz);
    dim3 gnn((ib+31)/32, (DN+31)/32);
    k_cgemm_nn<<<gnn,256,0,stream>>>(Tm, NB, G1, NB, G2, NB, ib, DN, ib, S, NB*DN);
    dim3 gup((m+63)/64, DN/64);
    k_cupdate64<<<gup,256,0,stream>>>(Vp, G2, Cre, Cim, row0, m, ib);
  }

  /* 5. V outputs (AH now dead) */
  {
    dim3 gt(DN/32, DN/32);
    k_outVre_t<<<gt,256,0,stream>>>(Cre, out);
  }
  k_outVinv<<<(DN*DN+255)/256,256,0,stream>>>(Cre, out + N2);
}

// Round 9
// 130115.442 us; speedup vs baseline: 3.2213x; 3.2213x over previous
//
#include <hip/hip_runtime.h>
#include <math.h>

#define DN 2048
#define LEAF 16
#define NLEAVES 128
#define NB 64
#define SPLITK 32
#define EPSF 5.9604645e-08f      /* slamch('E') = 2^-24 */
#define SAFMINF 1.17549435e-38f

typedef float2 cplx;

struct Ctl {
  float orgnrm;
  int K;
  int ctot[4];
  float rho;
  int nrot;
  int n12, n23;
};

__device__ __forceinline__ cplx mkc(float x, float y){ cplx c; c.x=x; c.y=y; return c; }
__device__ __forceinline__ cplx cmul(cplx a, cplx b){ return mkc(a.x*b.x - a.y*b.y, a.x*b.y + a.y*b.x); }
__device__ __forceinline__ cplx cconj(cplx a){ return mkc(a.x, -a.y); }
__device__ __forceinline__ cplx cadd(cplx a, cplx b){ return mkc(a.x+b.x, a.y+b.y); }
__device__ __forceinline__ cplx cinv(cplx b){
  if (fabsf(b.x) >= fabsf(b.y)) { float r = b.y/b.x; float den = b.x + b.y*r; return mkc(1.f/den, -r/den); }
  else { float r = b.x/b.y; float den = b.x*r + b.y; return mkc(r/den, -1.f/den); }
}

__global__ void k_zeroCnt(int* cnt){ if (threadIdx.x==0) *cnt = 0; }

/* ---------------- build H, LDS-tiled transpose reads ---------------- */
__global__ void k_buildH_t(const float* sk, cplx* AH){
  __shared__ float tA[32][33], tB[32][33];
  int C0 = blockIdx.x*32, R0 = blockIdx.y*32;
  int tx = threadIdx.x & 31, ty = threadIdx.x >> 5;
  for (int p=0;p<4;p++){
    int ry = ty + 8*p;
    tA[ry][tx] = sk[(size_t)(R0+ry)*DN + C0+tx];
    tB[ry][tx] = sk[(size_t)(C0+ry)*DN + R0+tx];
  }
  __syncthreads();
  for (int p=0;p<4;p++){
    int cy = ty + 8*p;
    int r = R0 + tx, c = C0 + cy;
    float im;
    if (r > c) im = -tB[cy][tx];
    else if (r < c) im = tA[tx][cy];
    else im = 0.f;
    AH[(size_t)c*DN + r] = mkc(copysignf(0.f, im), im);
  }
}

/* ---------------- chetd2 kernel 1: split-K matvec on RAW column + all partials +
   last-block finisher (clarfg + dot + scale). ---------------- */
__global__ void k_gemv3(cplx* AH, cplx* wpart, float* ssqpart,
                        cplx* dp, cplx* pa, cplx* a0copy, cplx* scl,
                        cplx* tauA, float* e, int* cnt, int j, int m, int chunk){
  __shared__ float rx[256], ry[256];
  __shared__ int slast;
  __shared__ cplx s_ssc;
  __shared__ int s_do;
  int t = threadIdx.x;
  int b = blockIdx.x, s = blockIdx.y;
  int i = b*256 + t;
  cplx* colr = AH + (size_t)j*DN;
  cplx* x = colr + (j+2);                  /* raw x[k], k < m-1 */
  int cc0 = s*chunk, cc1 = cc0+chunk; if (cc1 > m-1) cc1 = m-1;
  if (cc0 > m-1) cc0 = m-1;
  /* per-slice ssq partial (block b==0 of each slice) */
  if (b == 0){
    float ss = 0.f;
    for (int cc = cc0+t; cc < cc1; cc += 256){ cplx v = x[cc]; ss += v.x*v.x + v.y*v.y; }
    rx[t] = ss; __syncthreads();
    for (int q=128;q>0;q>>=1){ if (t<q) rx[t]+=rx[t+q]; __syncthreads(); }
    if (t==0) ssqpart[s] = rx[0];
    __syncthreads();
  }
  /* matvec partial on raw x */
  cplx acc = mkc(0.f,0.f);
  if (i < m){
    for (int cc = cc0; cc < cc1; ++cc){
      cplx a = AH[(size_t)(j+2+cc)*DN + (j+1+i)];
      cplx v = x[cc];
      acc.x += a.x*v.x - a.y*v.y;
      acc.y += a.x*v.y + a.y*v.x;
    }
    wpart[(size_t)s*DN + i] = acc;
  }
  /* a0 snapshot (slice 0) */
  cplx a0v = mkc(0.f,0.f);
  if (s == 0 && i < m){
    a0v = AH[(size_t)(j+1)*DN + (j+1+i)];
    a0copy[i] = a0v;
  }
  /* dot partial: dp[b,s] = sum_{i>=1} conj(wpart[s][i]) * x[i-1] */
  {
    float dxx=0.f, dyy=0.f;
    if (i >= 1 && i < m){
      cplx xv = x[i-1];
      dxx = acc.x*xv.x + acc.y*xv.y;
      dyy = acc.x*xv.y - acc.y*xv.x;
    }
    rx[t]=dxx; ry[t]=dyy; __syncthreads();
    for (int q=128;q>0;q>>=1){ if (t<q){ rx[t]+=rx[t+q]; ry[t]+=ry[t+q]; } __syncthreads(); }
    if (t==0) dp[b*SPLITK + s] = mkc(rx[0], ry[0]);
    __syncthreads();
  }
  /* a0-dot partial (slice 0): pa[b] = sum_{i>=1} conj(a0[i]) x[i-1] */
  if (s == 0){
    float px=0.f, py=0.f;
    if (i >= 1 && i < m){
      cplx xv = x[i-1];
      px = a0v.x*xv.x + a0v.y*xv.y;
      py = a0v.x*xv.y - a0v.y*xv.x;
    }
    rx[t]=px; ry[t]=py; __syncthreads();
    for (int q=128;q>0;q>>=1){ if (t<q){ rx[t]+=rx[t+q]; ry[t]+=ry[t+q]; } __syncthreads(); }
    if (t==0) pa[b] = mkc(rx[0], ry[0]);
    __syncthreads();
  }
  /* last-block election */
  __threadfence();
  if (t == 0){
    int total = gridDim.x * gridDim.y;
    int old = atomicAdd(cnt, 1);
    slast = (old == total-1) ? 1 : 0;
  }
  __syncthreads();
  if (!slast) return;
  __threadfence();
  int nb = gridDim.x;
  if (t == 0){
    *cnt = 0;
    float xn2 = 0.f;
    for (int q=0;q<SPLITK;q++) xn2 += ssqpart[q];
    cplx alpha = colr[j+1];
    if (sqrtf(xn2) == 0.f && alpha.y == 0.f){
      s_do = 0;
      tauA[j] = mkc(0.f,0.f); e[j] = alpha.x;
      scl[0] = mkc(0.f,0.f); scl[1] = mkc(0.f,0.f); scl[2] = mkc(0.f,0.f);
    } else {
      s_do = 1;
      float beta = -copysignf(sqrtf(alpha.x*alpha.x + alpha.y*alpha.y + xn2), alpha.x);
      cplx tj = mkc((beta - alpha.x)/beta, -alpha.y/beta);
      cplx ssc = cinv(mkc(alpha.x - beta, alpha.y));
      tauA[j] = tj; e[j] = beta;
      colr[j+1] = mkc(beta, 0.f);
      s_ssc = ssc;
      cplx P0 = mkc(0.f,0.f);
      for (int q=0;q<SPLITK;q++){ cplx u = wpart[(size_t)q*DN]; P0.x+=u.x; P0.y+=u.y; }
      cplx SP = mkc(0.f,0.f);
      for (int bb=0;bb<nb;bb++) for (int q=0;q<SPLITK;q++){ cplx u = dp[bb*SPLITK+q]; SP.x+=u.x; SP.y+=u.y; }
      cplx SA = mkc(0.f,0.f);
      for (int bb=0;bb<nb;bb++){ cplx u = pa[bb]; SA.x+=u.x; SA.y+=u.y; }
      cplx a0d = a0copy[0];
      cplx T1 = cadd(cconj(a0d), cmul(ssc, SA));
      cplx T2 = cadd(cconj(P0), cmul(ssc, SP));
      cplx dot = cmul(cconj(tj), cadd(T1, cmul(cconj(ssc), T2)));
      cplx td = cmul(tj, dot);
      scl[0] = tj; scl[1] = ssc; scl[2] = mkc(-td.x, 0.f);
    }
  }
  __syncthreads();
  if (s_do){
    cplx ssc = s_ssc;
    for (int r=j+2+t; r<DN; r+=256) colr[r] = cmul(colr[r], ssc);
  }
}

/* ---------------- chetd2 kernel 2: rank-2 update, 64x64 tiles, cooperative w-reconstruct
   u = v w'^H + w' v^H + a2 v v^H ---------------- */
__global__ void __launch_bounds__(256) k_her2w(cplx* AH, const cplx* wpart, const cplx* a0copy,
                        const cplx* scl, int j, int m){
  __shared__ cplx wsh[128];   /* w' for 64 rows, then 64 cols */
  __shared__ cplx vsh[128];
  __shared__ cplx part[256];
  int t = threadIdx.x;
  int r0 = blockIdx.x*64, c0 = blockIdx.y*64;
  cplx tj = scl[0], ssc = scl[1];
  float a2 = scl[2].x;
  const cplx* vcol = AH + (size_t)j*DN + (j+1);
  /* cooperative reconstruct: 128 indices x SPLITK slices, 2 threads/index */
  {
    int idx = t >> 1;
    int half = t & 1;
    int gi = (idx < 64) ? (r0 + idx) : (c0 + (idx-64));
    cplx P = mkc(0.f,0.f);
    if (gi < m){
      int s0 = half*(SPLITK/2);
      for (int s=s0; s<s0+(SPLITK/2); ++s){ cplx u = wpart[(size_t)s*DN + gi]; P.x+=u.x; P.y+=u.y; }
    }
    part[t] = P;
  }
  __syncthreads();
  if (t < 128){
    int gi = (t < 64) ? (r0 + t) : (c0 + (t-64));
    cplx wv = mkc(0.f,0.f), vv = mkc(0.f,0.f);
    if (gi < m){
      cplx P = cadd(part[2*t], part[2*t+1]);
      cplx av = cadd(a0copy[gi], cmul(ssc, P));
      wv = cmul(tj, av);
      vv = (gi==0)? mkc(1.f,0.f) : vcol[gi];
    }
    wsh[t] = wv; vsh[t] = vv;
  }
  __syncthreads();
  int rl = t & 15, cl = t >> 4;
  #pragma unroll
  for (int q=0;q<4;q++){
    int c = c0 + cl + 16*q;
    if (c >= m) continue;
    cplx vc = vsh[64 + cl + 16*q], wc = wsh[64 + cl + 16*q];
    #pragma unroll
    for (int i=0;i<4;i++){
      int r = r0 + rl + 16*i;
      if (r >= m) continue;
      cplx vr = vsh[rl + 16*i], wr = wsh[rl + 16*i];
      cplx u1 = cmul(vr, cconj(wc));
      cplx u2 = cmul(wr, cconj(vc));
      cplx u3 = cmul(vr, cconj(vc));
      size_t idx2 = (size_t)(j+1+c)*DN + (j+1+r);
      AH[idx2].x -= u1.x + u2.x + a2*u3.x;
      AH[idx2].y -= u1.y + u2.y + a2*u3.y;
    }
  }
}

__global__ void k_collectD(const cplx* AH, float* d){
  int i = blockIdx.x*256 + threadIdx.x;
  if (i < DN) d[i] = AH[(size_t)i*DN + i].x;
}

__global__ void k_zeroZ(float* Z){
  int idx = blockIdx.x*256 + threadIdx.x;
  if (idx < DN*DN) Z[idx] = 0.f;
}

/* ---------------- sstedc prep ---------------- */
__global__ void k_predc(float* d, float* e, int* indxq, Ctl* ctl){
  __shared__ float red[256];
  int t = threadIdx.x;
  float mx = 0.f;
  for (int i=t;i<DN;i+=256) mx = fmaxf(mx, fabsf(d[i]));
  for (int i=t;i<DN-1;i+=256) mx = fmaxf(mx, fabsf(e[i]));
  red[t]=mx; __syncthreads();
  for (int s=128;s>0;s>>=1){ if (t<s) red[t]=fmaxf(red[t],red[t+s]); __syncthreads(); }
  float orgnrm = red[0];
  if (t==0) ctl->orgnrm = orgnrm;
  float mul = 1.f/orgnrm;
  __syncthreads();
  for (int i=t;i<DN;i+=256) d[i]*=mul;
  for (int i=t;i<DN-1;i+=256) e[i]*=mul;
  __syncthreads();
  if (t==0){
    for (int b=1;b<NLEAVES;b++){ int s0=b*LEAF; float ae=fabsf(e[s0-1]); d[s0-1]-=ae; d[s0]-=ae; }
  }
  for (int i=t;i<DN;i+=256) indxq[i] = (i & (LEAF-1)) + 1;
}

/* ---------------- ssteqr (small, serial) ---------------- */
__device__ void slaev2_d(float a, float b, float c, float* rt1, float* rt2, float* cs1, float* sn1){
  float sm = a + c, df = a - c, adf = fabsf(df), tb = b + b, ab = fabsf(tb);
  float acmx, acmn;
  if (fabsf(a) > fabsf(c)) { acmx = a; acmn = c; } else { acmx = c; acmn = a; }
  float rt;
  if (adf > ab) rt = adf*sqrtf(1.f + (ab/adf)*(ab/adf));
  else if (adf < ab) rt = ab*sqrtf(1.f + (adf/ab)*(adf/ab));
  else rt = ab*sqrtf(2.f);
  int sgn1;
  if (sm < 0.f){ *rt1 = 0.5f*(sm - rt); sgn1 = -1; *rt2 = (acmx/(*rt1))*acmn - (b/(*rt1))*b; }
  else if (sm > 0.f){ *rt1 = 0.5f*(sm + rt); sgn1 = 1; *rt2 = (acmx/(*rt1))*acmn - (b/(*rt1))*b; }
  else { *rt1 = 0.5f*rt; *rt2 = -0.5f*rt; sgn1 = 1; }
  float cs; int sgn2;
  if (df >= 0.f){ cs = df + rt; sgn2 = 1; } else { cs = df - rt; sgn2 = -1; }
  float acs = fabsf(cs);
  if (acs > ab){ float ct = -tb/cs; *sn1 = 1.f/sqrtf(1.f + ct*ct); *cs1 = ct*(*sn1); }
  else {
    if (ab == 0.f){ *cs1 = 1.f; *sn1 = 0.f; }
    else { float tn = -cs/tb; *cs1 = 1.f/sqrtf(1.f + tn*tn); *sn1 = tn*(*cs1); }
  }
  if (sgn1 == sgn2){ float tn = *cs1; *cs1 = -(*sn1); *sn1 = tn; }
}

__device__ void slartg_d(float f, float g, float* cs, float* sn, float* r){
  if (g == 0.f){ *cs = 1.f; *sn = 0.f; *r = f; }
  else if (f == 0.f){ *cs = 0.f; *sn = copysignf(1.f, g); *r = fabsf(g); }
  else {
    float d = sqrtf(f*f + g*g);
    *cs = fabsf(f)/d;
    *r = copysignf(d, f);
    *sn = g/(*r);
  }
}

__device__ void rot1_d(float* z, int ldz, int nr, int col, float cc, float ss){
  for (int r=0;r<nr;++r){
    float tmp = z[(col+1)*ldz + r];
    z[(col+1)*ldz + r] = cc*tmp - ss*z[col*ldz + r];
    z[col*ldz + r] = ss*tmp + cc*z[col*ldz + r];
  }
}

__device__ void ssteqr_small(int n, float* d, float* e, float* z, int ldz){
  for (int c=0;c<n;c++) for (int r=0;r<n;r++) z[c*ldz+r] = (r==c)?1.f:0.f;
  const float eps=EPSF, eps2=eps*eps, safmin=SAFMINF;
  int nmaxit = n*30, jtot=0;
  int l1=0;
  float wc[LEAF], ws_[LEAF];
  while (1){
    if (l1 > n-1) break;
    if (l1 > 0) e[l1-1] = 0.f;
    int m;
    for (m = l1; m <= n-2; ++m){
      float tst = fabsf(e[m]);
      if (tst == 0.f) break;
      if (tst <= (sqrtf(fabsf(d[m]))*sqrtf(fabsf(d[m+1])))*eps){ e[m]=0.f; break; }
    }
    int l = l1, lend = m;
    l1 = m+1;
    if (lend == l) continue;
    if (fabsf(d[lend]) < fabsf(d[l])){ int tmp=l; l=lend; lend=tmp; }
    if (lend > l){
      while (1){
        int mm;
        if (l != lend){
          for (mm = l; mm <= lend-1; ++mm){
            float tst = e[mm]*e[mm];
            if (tst <= (eps2*fabsf(d[mm]))*fabsf(d[mm+1]) + safmin) break;
          }
        } else mm = lend;
        if (mm < lend) e[mm] = 0.f;
        float p = d[l];
        if (mm == l){ d[l]=p; l++; if (l<=lend) continue; else break; }
        if (mm == l+1){
          float rt1, rt2, c_, s_;
          slaev2_d(d[l], e[l], d[l+1], &rt1, &rt2, &c_, &s_);
          rot1_d(z, ldz, n, l, c_, s_);
          d[l]=rt1; d[l+1]=rt2; e[l]=0.f;
          l += 2; if (l<=lend) continue; else break;
        }
        if (jtot == nmaxit) break;
        jtot++;
        float g = (d[l+1]-p)/(2.f*e[l]);
        float rr = sqrtf(g*g+1.f);
        g = d[mm] - p + e[l]/(g + copysignf(rr, g));
        float s_ = 1.f, c_ = 1.f; p = 0.f;
        for (int i = mm-1; i >= l; --i){
          float f = s_*e[i], b = c_*e[i];
          slartg_d(g, f, &c_, &s_, &rr);
          if (i != mm-1) e[i+1] = rr;
          g = d[i+1] - p;
          rr = (d[i]-g)*s_ + 2.f*c_*b;
          p = s_*rr;
          d[i+1] = g+p;
          g = c_*rr - b;
          wc[i] = c_; ws_[i] = -s_;
        }
        for (int q = mm-1; q >= l; --q) rot1_d(z, ldz, n, q, wc[q], ws_[q]);
        d[l] = d[l] - p; e[l] = g;
      }
    } else {
      while (1){
        int mm;
        if (l != lend){
          for (mm = l; mm >= lend+1; --mm){
            float tst = e[mm-1]*e[mm-1];
            if (tst <= (eps2*fabsf(d[mm]))*fabsf(d[mm-1]) + safmin) break;
          }
        } else mm = lend;
        if (mm > lend) e[mm-1] = 0.f;
        float p = d[l];
        if (mm == l){ d[l]=p; l--; if (l>=lend) continue; else break; }
        if (mm == l-1){
          float rt1, rt2, c_, s_;
          slaev2_d(d[l-1], e[l-1], d[l], &rt1, &rt2, &c_, &s_);
          rot1_d(z, ldz, n, l-1, c_, s_);
          d[l-1]=rt1; d[l]=rt2; e[l-1]=0.f;
          l -= 2; if (l>=lend) continue; else break;
        }
        if (jtot == nmaxit) break;
        jtot++;
        float g = (d[l-1]-p)/(2.f*e[l-1]);
        float rr = sqrtf(g*g+1.f);
        g = d[mm] - p + e[l-1]/(g + copysignf(rr, g));
        float s_=1.f, c_=1.f; p=0.f;
        for (int i = mm; i <= l-1; ++i){
          float f = s_*e[i], b = c_*e[i];
          slartg_d(g, f, &c_, &s_, &rr);
          if (i != mm) e[i-1] = rr;
          g = d[i] - p;
          rr = (d[i+1]-g)*s_ + 2.f*c_*b;
          p = s_*rr;
          d[i] = g+p;
          g = c_*rr - b;
          wc[i] = c_; ws_[i] = s_;
        }
        for (int q = mm; q <= l-1; ++q) rot1_d(z, ldz, n, q, wc[q], ws_[q]);
        d[l] = d[l]-p; e[l-1] = g;
      }
    }
  }
  for (int ii=1; ii<n; ++ii){
    int i = ii-1, k = i; float pp = d[i];
    for (int jj=ii; jj<n; ++jj) if (d[jj] < pp){ k=jj; pp=d[jj]; }
    if (k != i){
      d[k]=d[i]; d[i]=pp;
      for (int r=0;r<n;r++){ float tv=z[i*ldz+r]; z[i*ldz+r]=z[k*ldz+r]; z[k*ldz+r]=tv; }
    }
  }
}

__global__ void k_leaves(float* d, float* e, float* Zmat){
  __shared__ float sd[LEAF], se[LEAF], sz[LEAF*LEAF];
  int off = blockIdx.x*LEAF;
  int t = threadIdx.x;
  if (t < LEAF){ sd[t] = d[off+t]; se[t] = (t<LEAF-1)? e[off+t] : 0.f; }
  __syncthreads();
  if (t==0) ssteqr_small(LEAF, sd, se, sz, LEAF);
  __syncthreads();
  if (t < LEAF){ d[off+t]=sd[t]; if (t<LEAF-1) e[off+t]=se[t]; }
  for (int i=t; i<LEAF*LEAF; i+=64){
    int c = i/LEAF, r = i%LEAF;
    Zmat[(size_t)(off+c)*DN + (off+r)] = sz[c*LEAF+r];
  }
}

/* ---------------- BATCHED merge prep: one block per merge, LDS-resident scan ---------------- */
__global__ void __launch_bounds__(256) k_mprep_b(
    float* d, const float* e, const float* Zmat, int* indxq,
    float* dlamda_g, float* wkeep_g, int* indx_g, int* indxc_g,
    float* rotc, float* rots, int* rotp, int* rotn,
    Ctl* ctls, int n)
{
  __shared__ float sz[2048];
  __shared__ float sdl[2048];
  __shared__ float sA[2048];
  __shared__ int   sB[2048];
  __shared__ int   sixl[2048];
  __shared__ int   sixp[2048];
  __shared__ int   sctp[2048];
  __shared__ float red[256];
  __shared__ float s_mz, s_md;
  int q = blockIdx.x;
  int off = q*n;
  int n1 = n/2, n2 = n - n1;
  Ctl* ctl = ctls + q;
  int t = threadIdx.x;
  float rho0 = e[off + n1 - 1];
  for (int c = t; c < n; c += 256){
    float val = (c < n1) ? Zmat[(size_t)(off+c)*DN + (off+n1-1)]
                         : Zmat[(size_t)(off+c)*DN + (off+n1)];
    if (c >= n1){ if (rho0 < 0.f) val = -val; indxq[off+c] += n1; }
    sz[c] = val * 0.70710678118654752440f;
    sdl[c] = d[off+c];
  }
  __syncthreads();
  for (int i = t; i < n; i += 256) sA[i] = sdl[indxq[off+i] - 1];
  __syncthreads();
  if (t == 0){
    int i1=0, i2=n1, ns1=n1, ns2=n2, k=0;
    while (ns1>0 && ns2>0){
      if (sA[i1] <= sA[i2]){ sB[k++]=i1+1; i1++; ns1--; }
      else { sB[k++]=i2+1; i2++; ns2--; }
    }
    while (ns1>0){ sB[k++]=i1+1; i1++; ns1--; }
    while (ns2>0){ sB[k++]=i2+1; i2++; ns2--; }
  }
  __syncthreads();
  for (int i = t; i < n; i += 256) sixl[i] = indxq[off + sB[i] - 1] - 1;
  __syncthreads();
  float mz=0.f, md=0.f;
  for (int i=t;i<n;i+=256){ mz = fmaxf(mz, fabsf(sz[i])); md = fmaxf(md, fabsf(sdl[i])); }
  red[t]=mz; __syncthreads();
  for (int s=128;s>0;s>>=1){ if (t<s) red[t]=fmaxf(red[t],red[t+s]); __syncthreads(); }
  if (t==0) s_mz = red[0];
  __syncthreads();
  red[t]=md; __syncthreads();
  for (int s=128;s>0;s>>=1){ if (t<s) red[t]=fmaxf(red[t],red[t+s]); __syncthreads(); }
  if (t==0) s_md = red[0];
  __syncthreads();
  if (t == 0){
    float rho = fabsf(2.f*rho0);
    float tol = 8.f*EPSF*fmaxf(s_md, s_mz);
    ctl->rho = rho;
    if (rho*s_mz <= tol){
      ctl->K = 0; ctl->nrot = 0;
      ctl->ctot[0]=0; ctl->ctot[1]=0; ctl->ctot[2]=0; ctl->ctot[3]=n;
      ctl->n12 = 0; ctl->n23 = 0;
    } else {
      for (int i=0;i<n1;i++) sctp[i]=0;
      for (int i=n1;i<n;i++) sctp[i]=2;
      int K=0, k2=n, nrot=0, pj=0;
      int jj=0;
      for (; jj<n; ++jj){
        int nj = sixl[jj];
        if (rho*fabsf(sz[nj]) <= tol){ k2--; sctp[nj]=3; sixp[k2]=nj; }
        else { pj = nj; break; }
      }
      for (;;){
        jj++;
        if (jj >= n) break;
        int nj = sixl[jj];
        if (rho*fabsf(sz[nj]) <= tol){ k2--; sctp[nj]=3; sixp[k2]=nj; }
        else {
          float s_ = sz[pj], c_ = sz[nj];
          float tau_ = sqrtf(c_*c_ + s_*s_);
          float tt = sdl[nj] - sdl[pj];
          c_ = c_/tau_; s_ = -s_/tau_;
          if (fabsf(tt*c_*s_) <= tol){
            sz[nj] = tau_; sz[pj] = 0.f;
            if (sctp[nj] != sctp[pj]) sctp[nj] = 1;
            sctp[pj] = 3;
            rotp[off+nrot]=pj; rotn[off+nrot]=nj; rotc[off+nrot]=c_; rots[off+nrot]=s_; nrot++;
            float t2 = sdl[pj]*c_*c_ + sdl[nj]*s_*s_;
            sdl[nj] = sdl[pj]*s_*s_ + sdl[nj]*c_*c_;
            sdl[pj] = t2;
            k2--;
            int ii = 1;
            for (;;){
              if (k2+ii <= n-1){
                if (sdl[pj] < sdl[sixp[k2+ii]]){ sixp[k2+ii-1]=sixp[k2+ii]; sixp[k2+ii]=pj; ii++; }
                else { sixp[k2+ii-1]=pj; break; }
              } else { sixp[k2+ii-1]=pj; break; }
            }
            pj = nj;
          } else {
            dlamda_g[off+K]=sdl[pj]; wkeep_g[off+K]=sz[pj]; sixp[K]=pj; K++;
            pj = nj;
          }
        }
      }
      dlamda_g[off+K]=sdl[pj]; wkeep_g[off+K]=sz[pj]; sixp[K]=pj; K++;
      int ct[4]={0,0,0,0};
      for (int q2=0;q2<n;q2++) ct[sctp[q2]]++;
      int psm[4]; psm[0]=0; psm[1]=ct[0]; psm[2]=ct[0]+ct[1]; psm[3]=ct[0]+ct[1]+ct[2];
      for (int q2=0;q2<n;q2++){
        int js = sixp[q2]; int cc = sctp[js];
        sixl[psm[cc]] = js; sB[psm[cc]] = q2; psm[cc]++;
      }
      ctl->K = K; ctl->nrot = nrot;
      ctl->ctot[0]=ct[0]; ctl->ctot[1]=ct[1]; ctl->ctot[2]=ct[2]; ctl->ctot[3]=ct[3];
      ctl->n12 = ct[0]+ct[1]; ctl->n23 = ct[1]+ct[2];
    }
  }
  __syncthreads();
  for (int i=t;i<n;i+=256){
    d[off+i] = sdl[i];
    indx_g[off+i] = sixl[i];
    indxc_g[off+i] = sB[i];
  }
}

__global__ void k_mrot_b(float* Zmat, const float* rotc, const float* rots,
                         const int* rotp, const int* rotn, const Ctl* ctls, int n){
  int q = blockIdx.y;
  int off = q*n;
  int r = blockIdx.x*256 + threadIdx.x;
  if (r >= n) return;
  int nrot = ctls[q].nrot;
  for (int p=0;p<nrot;++p){
    size_t ip = (size_t)(off+rotp[off+p])*DN + off + r;
    size_t in_ = (size_t)(off+rotn[off+p])*DN + off + r;
    float x = Zmat[ip], y = Zmat[in_];
    float cc = rotc[off+p], ss = rots[off+p];
    Zmat[ip]  = cc*x + ss*y;
    Zmat[in_] = cc*y - ss*x;
  }
}

__global__ void k_mcopyA_b(const float* d, const float* Zmat, float* Q2g, float* dgrp,
                           const int* indx, const Ctl* ctls, int n){
  int q = blockIdx.y;
  int off = q*n;
  int p = blockIdx.x;
  int t = threadIdx.x;
  int n1 = n/2, n2 = n - n1;
  const Ctl* ctl = ctls + q;
  float* Q2 = Q2g + (size_t)off*n;
  int c0 = ctl->ctot[0], c1 = ctl->ctot[1], c2 = ctl->ctot[2];
  int K = c0+c1+c2;
  int src = indx[off+p];
  const float* qcol = Zmat + (size_t)(off+src)*DN + off;
  if (t == 0) dgrp[off+p] = d[off+src];
  size_t base2 = (size_t)n1*(c0+c1);
  size_t base3 = base2 + (size_t)n2*(c1+c2);
  if (p < c0){
    float* dst = Q2 + (size_t)p*n1;
    for (int r=t;r<n1;r+=256) dst[r] = qcol[r];
  } else if (p < c0+c1){
    float* d1 = Q2 + (size_t)p*n1;
    float* d2 = Q2 + base2 + (size_t)(p-c0)*n2;
    for (int r=t;r<n1;r+=256) d1[r] = qcol[r];
    for (int r=t;r<n2;r+=256) d2[r] = qcol[n1+r];
  } else if (p < K){
    float* d2 = Q2 + base2 + (size_t)(p-c0)*n2;
    for (int r=t;r<n2;r+=256) d2[r] = qcol[n1+r];
  } else {
    float* dst = Q2 + base3 + (size_t)(p-K)*n;
    for (int r=t;r<n;r+=256) dst[r] = qcol[r];
  }
}

__global__ void k_mcopyB_b(float* d, float* Zmat, const float* Q2g, const float* dgrp,
                           const Ctl* ctls, int n){
  int q = blockIdx.y;
  int off = q*n;
  int p = blockIdx.x;
  int t = threadIdx.x;
  int n1 = n/2, n2 = n - n1;
  const Ctl* ctl = ctls + q;
  const float* Q2 = Q2g + (size_t)off*n;
  int c0 = ctl->ctot[0], c1 = ctl->ctot[1], c2 = ctl->ctot[2];
  int K = c0+c1+c2;
  if (p < K) return;
  size_t base3 = (size_t)n1*(c0+c1) + (size_t)n2*(c1+c2);
  const float* src = Q2 + base3 + (size_t)(p-K)*n;
  float* dst = Zmat + (size_t)(off+p)*DN + off;
  for (int r=t;r<n;r+=256) dst[r] = src[r];
  if (t==0) d[off+p] = dgrp[off+p];
}

__global__ void k_msec_b(float* d, float* Zmat, const float* dl_g, const float* w_g,
                         const Ctl* ctls, int n){
  int q = blockIdx.y;
  int off = q*n;
  int j = blockIdx.x*64 + threadIdx.x;
  int K = ctls[q].K;
  if (j >= K) return;
  float rho = ctls[q].rho;
  const float* dl = dl_g + off;
  const float* w = w_g + off;
  float* delta = Zmat + (size_t)(off+j)*DN + off;
  if (K == 1){
    d[off] = dl[0] + rho*w[0]*w[0];
    delta[0] = 1.f;
    return;
  }
  int orig; float lo, hi;
  if (j < K-1){
    float gap = dl[j+1] - dl[j];
    float half = 0.5f*gap;
    float fmid = 1.f;
    for (int l=0;l<K;l++){
      float D = (dl[l]-dl[j]) - half;
      fmid += rho*w[l]*w[l]/D;
    }
    if (fmid >= 0.f){ orig = j;   lo = 0.f;   hi = half; }
    else            { orig = j+1; lo = -half; hi = 0.f;  }
  } else {
    float s2 = 0.f;
    for (int l=0;l<K;l++) s2 += w[l]*w[l];
    orig = K-1; lo = 0.f; hi = rho*s2*1.000002f + 1e-30f;
  }
  float dorig = dl[orig];
  float eta = 0.5f*(lo+hi);
  for (int it=0; it<50; ++it){
    float g = 1.f, gp = 0.f;
    for (int l=0;l<K;l++){
      float del = (dl[l]-dorig) - eta;
      float r = w[l]/del;
      g  += rho*w[l]*r;
      gp += rho*r*r;
    }
    if (g > 0.f) hi = eta; else lo = eta;
    float etan = eta - g/gp;
    if (!(etan > lo && etan < hi)) etan = 0.5f*(lo+hi);
    if (etan == eta) break;
    eta = etan;
  }
  d[off+j] = dorig + eta;
  for (int l=0;l<K;l++) delta[l] = (dl[l]-dorig) - eta;
}

__global__ void k_mzhat_b(const float* dl_g, const float* w_g, float* what,
                          const float* Zmat, const Ctl* ctls, int n){
  int q = blockIdx.y;
  int off = q*n;
  int K = ctls[q].K;
  int i = blockIdx.x*64 + threadIdx.x;
  if (i >= K) return;
  const float* dlamda = dl_g + off;
  float acc = Zmat[(size_t)(off+i)*DN + off+i];
  float di = dlamda[i];
  for (int jj=0;jj<K;jj++){
    if (jj==i) continue;
    acc *= Zmat[(size_t)(off+jj)*DN + off+i] / (di - dlamda[jj]);
  }
  what[off+i] = copysignf(sqrtf(fabsf(acc)), w_g[off+i]);
}

__global__ void k_mvec_b(float* Zmat, const float* what, const int* indxc,
                         const Ctl* ctls, int n){
  __shared__ float sv[2048];
  __shared__ float red[256];
  int q = blockIdx.y;
  int off = q*n;
  int K = ctls[q].K;
  int j = blockIdx.x;
  if (j >= K) return;
  int t = threadIdx.x;
  float* col = Zmat + (size_t)(off+j)*DN + off;
  float ssq = 0.f;
  for (int i=t;i<K;i+=256){
    float den = col[i];
    if (den == 0.f) den = 1e-30f;
    float v = what[off+i]/den; sv[i]=v; ssq += v*v;
  }
  red[t]=ssq; __syncthreads();
  for (int s=128;s>0;s>>=1){ if (t<s) red[t]+=red[t+s]; __syncthreads(); }
  float temp = sqrtf(red[0]);
  for (int i=t;i<K;i+=256) col[i] = sv[indxc[off+i]]/temp;
}

__global__ void k_mcopyS_b(float* Smatg, const float* Zmat, const Ctl* ctls, int n, int mode){
  int q = blockIdx.y;
  int off = q*n;
  const Ctl* ctl = ctls + q;
  int K = ctl->K; if (K==0) return;
  int rows = (mode==1)? ctl->n23 : ctl->n12;
  int rowoff = (mode==1)? ctl->ctot[0] : 0;
  if (rows==0) return;
  float* Smat = Smatg + (size_t)off*n;
  size_t tot = (size_t)rows*K;
  for (size_t idx = (size_t)blockIdx.x*256+threadIdx.x; idx < tot; idx += (size_t)gridDim.x*256){
    int r = (int)(idx % rows); int c = (int)(idx / rows);
    Smat[idx] = Zmat[(size_t)(off+c)*DN + off + rowoff + r];
  }
}

__global__ void k_sgemm_dc64_b(float* Zmat, const float* Q2g, const float* Smatg,
                               const Ctl* ctls, int n, int mode){
  int q = blockIdx.z;
  int off = q*n;
  const Ctl* ctl = ctls + q;
  int K = ctl->K; if (K==0) return;
  int n1 = n/2, n2 = n-n1;
  const float* Q2 = Q2g + (size_t)off*n;
  const float* Smat = Smatg + (size_t)off*n;
  int m, kd; const float* A; int lda; float* C;
  if (mode==1){ m=n2; kd=ctl->n23; A = Q2 + (size_t)n1*ctl->n12; lda=n2; C = Zmat + (size_t)off*DN + off+n1; }
  else { m=n1; kd=ctl->n12; A = Q2; lda=n1; C = Zmat + (size_t)off*DN + off; }
  int tr = blockIdx.x*64, tc = blockIdx.y*64;
  if (tr >= m || tc >= K) return;
  __shared__ float As[64][17], Bs[16][65];
  int tid = threadIdx.x, tx = tid & 15, ty = tid >> 4;
  float acc[4][4];
  #pragma unroll
  for (int i=0;i<4;i++) for (int jq=0;jq<4;jq++) acc[i][jq]=0.f;
  for (int k0=0;k0<kd;k0+=16){
    #pragma unroll
    for (int p=0;p<4;p++){
      int r = tid & 63, kk = (tid >> 6) + 4*p;
      As[r][kk] = (tr+r<m && k0+kk<kd) ? A[(size_t)(k0+kk)*lda + tr+r] : 0.f;
    }
    #pragma unroll
    for (int p=0;p<4;p++){
      int kk = tid & 15, c = (tid >> 4) + 16*p;
      Bs[kk][c] = (k0+kk<kd && tc+c<K) ? Smat[(size_t)(tc+c)*kd + k0+kk] : 0.f;
    }
    __syncthreads();
    #pragma unroll
    for (int k=0;k<16;k++){
      float a[4], b[4];
      #pragma unroll
      for (int i=0;i<4;i++){ a[i]=As[tx+16*i][k]; b[i]=Bs[k][ty+16*i]; }
      #pragma unroll
      for (int i=0;i<4;i++)
        #pragma unroll
        for (int jq=0;jq<4;jq++) acc[i][jq] += a[i]*b[jq];
    }
    __syncthreads();
  }
  #pragma unroll
  for (int i=0;i<4;i++)
    #pragma unroll
    for (int jq=0;jq<4;jq++){
      int r = tr+tx+16*i, c = tc+ty+16*jq;
      if (r < m && c < K) C[(size_t)c*DN + r] = acc[i][jq];
    }
}

__global__ void __launch_bounds__(256) k_mmerge_b(float* d, int* indxq, const Ctl* ctls, int n){
  __shared__ float sd[2048];
  __shared__ int sq[2048];
  int q = blockIdx.x;
  int off = q*n;
  int t = threadIdx.x;
  int K = ctls[q].K;
  if (K == 0){
    for (int i=t;i<n;i+=256) indxq[off+i] = i+1;
    return;
  }
  for (int i=t;i<n;i+=256) sd[i] = d[off+i];
  __syncthreads();
  if (t == 0){
    int i1=0, i2=n-1, ns1=K, ns2=n-K, k=0;
    while (ns1>0 && ns2>0){
      if (sd[i1] <= sd[i2]){ sq[k++]=i1+1; i1++; ns1--; }
      else { sq[k++]=i2+1; i2--; ns2--; }
    }
    while (ns1>0){ sq[k++]=i1+1; i1++; ns1--; }
    while (ns2>0){ sq[k++]=i2+1; i2--; ns2--; }
  }
  __syncthreads();
  for (int i=t;i<n;i+=256) indxq[off+i] = sq[i];
}

/* ---------------- final permutation + scale back ---------------- */
__global__ void k_fpermA(const float* d, const float* Zmat, float* Q2, float* dtmp, const int* indxq){
  int i = blockIdx.x; int t = threadIdx.x;
  int src = indxq[i]-1;
  if (t==0) dtmp[i] = d[src];
  const float* sc = Zmat + (size_t)src*DN;
  float* dc = Q2 + (size_t)i*DN;
  for (int r=t;r<DN;r+=256) dc[r]=sc[r];
}
__global__ void k_fpermB(float* evals, float* Zmat, const float* Q2, const float* dtmp, const Ctl* ctl){
  int i = blockIdx.x; int t = threadIdx.x;
  if (t==0) evals[i] = dtmp[i]*ctl->orgnrm;
  const float* sc = Q2 + (size_t)i*DN;
  float* dc = Zmat + (size_t)i*DN;
  for (int r=t;r<DN;r+=256) dc[r]=sc[r];
}

/* ---------------- cunmqr on split re/im planes ---------------- */
__global__ void k_packV(const cplx* AH, cplx* Vp, int i0, int ib, int m){
  int idx = blockIdx.x*256 + threadIdx.x;
  if (idx >= m*ib) return;
  int r = idx % m, c = idx / m;
  int grow = i0+1+r, pc = i0+c+1;
  cplx v;
  if (grow < pc) v = mkc(0.f,0.f);
  else if (grow == pc) v = mkc(1.f,0.f);
  else v = AH[(size_t)(i0+c)*DN + grow];
  Vp[(size_t)c*m + r] = v;
}

/* one block per (r,c) pair */
__global__ void k_vhv2(const cplx* Vp, cplx* vhv, int m, int ib){
  __shared__ float rx[256], ry[256];
  int r = blockIdx.x, c = blockIdx.y;
  if (r >= c || c >= ib) return;
  int t = threadIdx.x;
  float dx=0.f, dy=0.f;
  for (int rl=c+t; rl<m; rl+=256){
    cplx a = Vp[(size_t)r*m + rl];
    cplx b = Vp[(size_t)c*m + rl];
    dx += a.x*b.x + a.y*b.y;
    dy += a.x*b.y - a.y*b.x;
  }
  rx[t]=dx; ry[t]=dy; __syncthreads();
  for (int s=128;s>0;s>>=1){ if (t<s){ rx[t]+=rx[t+s]; ry[t]+=ry[t+s]; } __syncthreads(); }
  if (t==0) vhv[r + c*NB] = mkc(rx[0], ry[0]);
}

__global__ void k_bldT(const cplx* vhv, const cplx* tau, cplx* T, int ib){
  int t = threadIdx.x;
  for (int idx=t; idx<NB*NB; idx+=64) T[idx] = mkc(0.f,0.f);
  __syncthreads();
  for (int c=0; c<ib; ++c){
    if (t < c){
      cplx acc = mkc(0.f,0.f);
      for (int q=t; q<c; ++q) acc = cadd(acc, cmul(T[t + q*NB], vhv[q + c*NB]));
      cplx nt = mkc(-tau[c].x, -tau[c].y);
      T[t + c*NB] = cmul(nt, acc);
    }
    if (t == c) T[c + c*NB] = tau[c];
    __syncthreads();
  }
}

__global__ void k_cgemm_ct64(const cplx* A, const float* Cre, const float* Cim,
                             cplx* G1, int row0, int m, int ib, int ksz){
  int tc = blockIdx.y*64;
  int s = blockIdx.z;
  int ks0 = s*ksz, ks1 = ks0 + ksz; if (ks1 > m) ks1 = m;
  __shared__ cplx As[64][17], Bs[16][65];
  int tid = threadIdx.x, tx = tid & 15, ty = tid >> 4;
  cplx acc[4][4];
  #pragma unroll
  for (int i=0;i<4;i++) for (int jq=0;jq<4;jq++) acc[i][jq]=mkc(0.f,0.f);
  for (int k0 = ks0; k0 < ks1; k0 += 16){
    #pragma unroll
    for (int p=0;p<4;p++){
      int kk = tid & 15, r = (tid >> 4) + 16*p;
      cplx v = mkc(0.f,0.f);
      if (r < ib && k0+kk < ks1) v = cconj(A[(size_t)r*m + k0+kk]);
      As[r][kk] = v;
    }
    #pragma unroll
    for (int p=0;p<4;p++){
      int kk = tid & 15, c = (tid >> 4) + 16*p;
      cplx v = mkc(0.f,0.f);
      int kg = k0+kk, cg = tc+c;
      if (kg < ks1 && cg < DN){ size_t bi = (size_t)cg*DN + row0 + kg; v = mkc(Cre[bi], Cim[bi]); }
      Bs[kk][c] = v;
    }
    __syncthreads();
    #pragma unroll
    for (int k=0;k<16;k++){
      cplx a[4], b[4];
      #pragma unroll
      for (int i=0;i<4;i++){ a[i]=As[tx+16*i][k]; b[i]=Bs[k][ty+16*i]; }
      #pragma unroll
      for (int i=0;i<4;i++)
        #pragma unroll
        for (int jq=0;jq<4;jq++){
          acc[i][jq].x += a[i].x*b[jq].x - a[i].y*b[jq].y;
          acc[i][jq].y += a[i].x*b[jq].y + a[i].y*b[jq].x;
        }
    }
    __syncthreads();
  }
  #pragma unroll
  for (int i=0;i<4;i++)
    #pragma unroll
    for (int jq=0;jq<4;jq++){
      int r = tx+16*i, c = tc+ty+16*jq;
      if (r < ib && c < DN) G1[(size_t)s*NB*DN + r + (size_t)c*NB] = acc[i][jq];
    }
}

__global__ void k_cgemm_nn(const cplx* A, int lda, const cplx* B, int ldb,
                           cplx* C, int ldc, int m, int nn, int kk, int S, int ssz){
  __shared__ cplx As[32][33], Bs[32][33];
  int tr = blockIdx.x*32, tc = blockIdx.y*32;
  if (tr >= m || tc >= nn) return;
  int tx = threadIdx.x & 31, ty = threadIdx.x >> 5;
  cplx acc[4]; for (int q=0;q<4;q++) acc[q]=mkc(0.f,0.f);
  for (int k0=0;k0<kk;k0+=32){
    for (int q=0;q<4;q++){ int kc=k0+ty+q*8; int r=tr+tx;
      As[tx][ty+q*8] = (r<m && kc<kk)? A[(size_t)kc*lda + r] : mkc(0.f,0.f); }
    for (int q=0;q<4;q++){ int cc=tc+ty+q*8; int kr=k0+tx;
      cplx v = mkc(0.f,0.f);
      if (kr<kk && cc<nn){
        for (int s=0;s<S;s++){ cplx u = B[(size_t)s*ssz + kr + (size_t)cc*ldb]; v.x+=u.x; v.y+=u.y; }
      }
      Bs[tx][ty+q*8] = v; }
    __syncthreads();
    for (int kq=0;kq<32;kq++){
      cplx a = As[tx][kq];
      #pragma unroll
      for (int q=0;q<4;q++){
        cplx b = Bs[kq][ty+q*8];
        acc[q].x += a.x*b.x - a.y*b.y;
        acc[q].y += a.x*b.y + a.y*b.x;
      }
    }
    __syncthreads();
  }
  int r = tr+tx;
  if (r < m){
    for (int q=0;q<4;q++){ int c = tc+ty+q*8; if (c < nn) C[r + (size_t)c*NB] = acc[q]; }
  }
}

__global__ void k_cupdate64(const cplx* A, const cplx* G2, float* Cre, float* Cim,
                            int row0, int m, int ib){
  int tr = blockIdx.x*64, tc = blockIdx.y*64;
  if (tr >= m) return;
  __shared__ cplx As[64][17], Bs[16][65];
  int tid = threadIdx.x, tx = tid & 15, ty = tid >> 4;
  cplx acc[4][4];
  #pragma unroll
  for (int i=0;i<4;i++) for (int jq=0;jq<4;jq++) acc[i][jq]=mkc(0.f,0.f);
  for (int k0=0;k0<ib;k0+=16){
    #pragma unroll
    for (int p=0;p<4;p++){
      int r = tid & 63, kk = (tid >> 6) + 4*p;
      As[r][kk] = (tr+r<m && k0+kk<ib)? A[(size_t)(k0+kk)*m + tr+r] : mkc(0.f,0.f);
    }
    #pragma unroll
    for (int p=0;p<4;p++){
      int kk = tid & 15, c = (tid >> 4) + 16*p;
      Bs[kk][c] = (k0+kk<ib && tc+c<DN)? G2[(k0+kk) + (size_t)(tc+c)*NB] : mkc(0.f,0.f);
    }
    __syncthreads();
    #pragma unroll
    for (int k=0;k<16;k++){
      cplx a[4], b[4];
      #pragma unroll
      for (int i=0;i<4;i++){ a[i]=As[tx+16*i][k]; b[i]=Bs[k][ty+16*i]; }
      #pragma unroll
      for (int i=0;i<4;i++)
        #pragma unroll
        for (int jq=0;jq<4;jq++){
          acc[i][jq].x += a[i].x*b[jq].x - a[i].y*b[jq].y;
          acc[i][jq].y += a[i].x*b[jq].y + a[i].y*b[jq].x;
        }
    }
    __syncthreads();
  }
  #pragma unroll
  for (int i=0;i<4;i++)
    #pragma unroll
    for (int jq=0;jq<4;jq++){
      int r = tr+tx+16*i, c = tc+ty+16*jq;
      if (r < m && c < DN){
        size_t idx = (size_t)c*DN + row0 + r;
        Cre[idx] -= acc[i][jq].x;
        Cim[idx] -= acc[i][jq].y;
      }
    }
}

/* ---------------- outputs (real parts only) ---------------- */
__global__ void k_outVre_t(const float* Cre, float* out0){
  __shared__ float tile[32][33];
  int C0 = blockIdx.x*32, R0 = blockIdx.y*32;
  int tx = threadIdx.x & 31, ty = threadIdx.x >> 5;
  for (int p=0;p<4;p++){
    int cy = ty + 8*p;
    tile[cy][tx] = Cre[(size_t)(C0+cy)*DN + R0+tx];
  }
  __syncthreads();
  for (int p=0;p<4;p++){
    int ry = ty + 8*p;
    out0[(size_t)(R0+ry)*DN + C0+tx] = tile[tx][ry];
  }
}
__global__ void k_outVinv(const float* Cre, float* out1){
  int idx = blockIdx.x*256 + threadIdx.x;
  if (idx >= DN*DN) return;
  out1[idx] = Cre[idx];
}
__global__ void k_outEvo(const float* evals, const float* dt, float* out2, int T){
  int idx = blockIdx.x*256 + threadIdx.x;
  if (idx >= T*DN) return;
  int k = idx & (DN-1), tt = idx >> 11;
  out2[idx] = cosf(evals[k]*dt[tt]);
}

/* ---------------- host ---------------- */
extern "C" void kernel_launch(void* const* d_in, const int* in_sizes, int n_in,
                              void* d_out, int out_size, void* d_ws, size_t ws_size,
                              hipStream_t stream)
{
  const float* sk = (const float*)d_in[0];
  const float* dt = (const float*)d_in[1];
  int Ttot = in_sizes[1];
  float* out = (float*)d_out;
  (void)n_in; (void)out_size;

  const size_t N2 = (size_t)DN*DN;
  cplx*  AH   = (cplx*)out;
  float* Smat = out + 2*N2;
  float* Zmat = (float*)d_ws;           /* = Cre */
  float* Q2   = (float*)d_ws + N2;      /* = Cim */
  float* Cre  = Zmat;
  float* Cim  = Q2;

  char* wp = (char*)d_ws + 2*N2*sizeof(float);
  auto carve = [&](size_t b)->void*{ void* p=(void*)wp; wp += (b+255)&~(size_t)255; return p; };
  float* dd     = (float*)carve(DN*sizeof(float));
  float* ee     = (float*)carve(DN*sizeof(float));
  float* dtmp   = (float*)carve(DN*sizeof(float));
  float* dlamda = (float*)carve(DN*sizeof(float));
  float* wkeep  = (float*)carve(DN*sizeof(float));
  float* what   = (float*)carve(DN*sizeof(float));
  float* dgrp   = (float*)carve(DN*sizeof(float));
  float* rotc   = (float*)carve(DN*sizeof(float));
  float* rots   = (float*)carve(DN*sizeof(float));
  float* evals  = (float*)carve(DN*sizeof(float));
  float* ssqpart= (float*)carve(64*sizeof(float));
  cplx*  tauA   = (cplx*)carve(DN*sizeof(cplx));
  cplx*  a0copy = (cplx*)carve(DN*sizeof(cplx));
  cplx*  dp     = (cplx*)carve(512*sizeof(cplx));
  cplx*  pa     = (cplx*)carve(64*sizeof(cplx));
  cplx*  scl    = (cplx*)carve(8*sizeof(cplx));
  int*   cnt    = (int*)carve(16*sizeof(int));
  int*   indxq  = (int*)carve(DN*sizeof(int));
  int*   indx   = (int*)carve(DN*sizeof(int));
  int*   indxc  = (int*)carve(DN*sizeof(int));
  int*   rotp   = (int*)carve(DN*sizeof(int));
  int*   rotn   = (int*)carve(DN*sizeof(int));
  Ctl*   ctlG   = (Ctl*)carve(sizeof(Ctl));
  Ctl*   ctls   = (Ctl*)carve(NLEAVES*sizeof(Ctl));
  cplx*  Vp     = (cplx*)carve((size_t)DN*NB*sizeof(cplx));   /* wpart [SPLITK][DN] aliases */
  cplx*  G2     = (cplx*)carve((size_t)NB*DN*sizeof(cplx));
  cplx*  Tm     = (cplx*)carve((size_t)NB*NB*sizeof(cplx));
  cplx*  vhv    = (cplx*)carve((size_t)NB*NB*sizeof(cplx));
  size_t used = (size_t)(wp - (char*)d_ws);
  int S = 8;
  while (S > 1 && (ws_size != 0) && (used + (size_t)S*NB*DN*sizeof(cplx) > ws_size)) S >>= 1;
  if (ws_size == 0) S = 1;
  cplx*  G1     = (cplx*)carve((size_t)S*NB*DN*sizeof(cplx));
  cplx*  wpart  = Vp;

  k_zeroCnt<<<1,1,0,stream>>>(cnt);

  /* 1. build H */
  {
    dim3 gb(DN/32, DN/32);
    k_buildH_t<<<gb,256,0,stream>>>(sk, AH);
  }

  /* 2. chetd2 lower (2-kernel chain per column) */
  for (int j=0; j<=DN-2; ++j){
    int m = DN-1-j;
    int chunk = (m-1 + SPLITK - 1)/SPLITK;
    dim3 gv((m+255)/256, SPLITK);
    k_gemv3<<<gv,256,0,stream>>>(AH, wpart, ssqpart, dp, pa, a0copy, scl, tauA, ee, cnt, j, m, chunk);
    dim3 g2((m+63)/64,(m+63)/64);
    k_her2w<<<g2,256,0,stream>>>(AH, wpart, a0copy, scl, j, m);
  }
  k_collectD<<<(DN+255)/256,256,0,stream>>>(AH, dd);

  /* 3. sstedc('I') equivalent (real D&C, level-batched) */
  k_zeroZ<<<(DN*DN+255)/256,256,0,stream>>>(Zmat);
  k_predc<<<1,256,0,stream>>>(dd, ee, indxq, ctlG);
  k_leaves<<<NLEAVES,64,0,stream>>>(dd, ee, Zmat);

  for (int szv = LEAF; szv < DN; szv *= 2){
    int n = 2*szv;
    int M = DN/n;
    k_mprep_b<<<M,256,0,stream>>>(dd, ee, Zmat, indxq, dlamda, wkeep, indx, indxc,
                                  rotc, rots, rotp, rotn, ctls, n);
    k_mrot_b<<<dim3((n+255)/256, M),256,0,stream>>>(Zmat, rotc, rots, rotp, rotn, ctls, n);
    k_mcopyA_b<<<dim3(n, M),256,0,stream>>>(dd, Zmat, Q2, dgrp, indx, ctls, n);
    k_mcopyB_b<<<dim3(n, M),256,0,stream>>>(dd, Zmat, Q2, dgrp, ctls, n);
    k_msec_b<<<dim3((n+63)/64, M),64,0,stream>>>(dd, Zmat, dlamda, wkeep, ctls, n);
    k_mzhat_b<<<dim3((n+63)/64, M),64,0,stream>>>(dlamda, wkeep, what, Zmat, ctls, n);
    k_mvec_b<<<dim3(n, M),256,0,stream>>>(Zmat, what, indxc, ctls, n);
    int gcs = ((n*n)+255)/256; if (gcs > 4096) gcs = 4096;
    k_mcopyS_b<<<dim3(gcs, M),256,0,stream>>>(Smat, Zmat, ctls, n, 1);
    dim3 gg((n+63)/64,(n+63)/64,M);
    k_sgemm_dc64_b<<<gg,256,0,stream>>>(Zmat, Q2, Smat, ctls, n, 1);
    k_mcopyS_b<<<dim3(gcs, M),256,0,stream>>>(Smat, Zmat, ctls, n, 2);
    k_sgemm_dc64_b<<<gg,256,0,stream>>>(Zmat, Q2, Smat, ctls, n, 2);
    k_mmerge_b<<<M,256,0,stream>>>(dd, indxq, ctls, n);
  }
  k_fpermA<<<DN,256,0,stream>>>(dd, Zmat, Q2, dtmp, indxq);
  k_fpermB<<<DN,256,0,stream>>>(evals, Zmat, Q2, dtmp, ctlG);

  /* evo output (Smat region dead; evals in d_ws) */
  k_outEvo<<<((Ttot*DN)+255)/256,256,0,stream>>>(evals, dt, out + 2*N2, Ttot);

  /* 4. cunmqr on split planes: Cre = Zmat (in place), Cim = 0 */
  k_zeroZ<<<(DN*DN+255)/256,256,0,stream>>>(Cim);
  int Krefl = DN-1;
  for (int i0 = ((Krefl-1)/NB)*NB; i0 >= 0; i0 -= NB){
    int ib = Krefl - i0; if (ib > NB) ib = NB;
    int m = DN-1-i0;
    int row0 = i0+1;
    k_packV<<<((m*ib)+255)/256,256,0,stream>>>(AH, Vp, i0, ib, m);
    dim3 gvh(ib, ib);
    k_vhv2<<<gvh,256,0,stream>>>(Vp, vhv, m, ib);
    k_bldT<<<1,64,0,stream>>>(vhv, tauA+i0, Tm, ib);
    int ksz = ((m + S - 1)/S + 15) & ~15;
    dim3 gct(1, DN/64, S);
    k_cgemm_ct64<<<gct,256,0,stream>>>(Vp, Cre, Cim, G1, row0, m, ib, ksz);
    dim3 gnn((ib+31)/32, (DN+31)/32);
    k_cgemm_nn<<<gnn,256,0,stream>>>(Tm, NB, G1, NB, G2, NB, ib, DN, ib, S, NB*DN);
    dim3 gup((m+63)/64, DN/64);
    k_cupdate64<<<gup,256,0,stream>>>(Vp, G2, Cre, Cim, row0, m, ib);
  }

  /* 5. V outputs (AH now dead) */
  {
    dim3 gt(DN/32, DN/32);
    k_outVre_t<<<gt,256,0,stream>>>(Cre, out);
  }
  k_outVinv<<<(DN*DN+255)/256,256,0,stream>>>(Cre, out + N2);
}